// Round 1
// baseline (710.213 us; speedup 1.0000x reference)
//
#include <hip/hip_runtime.h>

#define NN   1024
#define NE   16384
#define HID  128
#define ND   133
#define BD   14
#define KIN  147   // ND + BD
#define NVMAX 128
#define EB   8     // edges per block in edge kernels

// ---------------- shared device math (bit-identical across kernels) ----------------

__device__ __forceinline__ float sigm(float x) { return 1.0f / (1.0f + expf(-x)); }

// one gate iteration: r = r * (1 - sigmoid(r @ Wg + bg)); r lives in LDS (HID floats)
__device__ __forceinline__ void gate_step(float* rS, const float* __restrict__ Wg,
                                          const float* __restrict__ bg, int tid) {
    float g = 0.0f;
    if (tid < HID) {
        float t0 = 0.f, t1 = 0.f, t2 = 0.f, t3 = 0.f;
        for (int k = 0; k < HID; k += 4) {
            t0 = fmaf(rS[k + 0], Wg[(k + 0) * HID + tid], t0);
            t1 = fmaf(rS[k + 1], Wg[(k + 1) * HID + tid], t1);
            t2 = fmaf(rS[k + 2], Wg[(k + 2) * HID + tid], t2);
            t3 = fmaf(rS[k + 3], Wg[(k + 3) * HID + tid], t3);
        }
        float t = ((t0 + t1) + (t2 + t3)) + bg[tid];
        g = 1.0f - sigm(t);
    }
    __syncthreads();
    if (tid < HID) rS[tid] *= g;
    __syncthreads();
}

// two hidden layers 128->256->64 with relu; needs >=256 threads; h1[256], h2[64] in LDS
__device__ __forceinline__ void mlp_256_64(const float* rS, float* h1, float* h2,
                                           const float* __restrict__ W1, const float* __restrict__ b1,
                                           const float* __restrict__ W2, const float* __restrict__ b2,
                                           int tid) {
    if (tid < 256) {
        float a0 = 0.f, a1 = 0.f, a2 = 0.f, a3 = 0.f;
        for (int k = 0; k < HID; k += 4) {
            a0 = fmaf(rS[k + 0], W1[(k + 0) * 256 + tid], a0);
            a1 = fmaf(rS[k + 1], W1[(k + 1) * 256 + tid], a1);
            a2 = fmaf(rS[k + 2], W1[(k + 2) * 256 + tid], a2);
            a3 = fmaf(rS[k + 3], W1[(k + 3) * 256 + tid], a3);
        }
        h1[tid] = fmaxf(((a0 + a1) + (a2 + a3)) + b1[tid], 0.f);
    }
    __syncthreads();
    if (tid < 64) {
        float a0 = 0.f, a1 = 0.f, a2 = 0.f, a3 = 0.f;
        for (int k = 0; k < 256; k += 4) {
            a0 = fmaf(h1[k + 0], W2[(k + 0) * 64 + tid], a0);
            a1 = fmaf(h1[k + 1], W2[(k + 1) * 64 + tid], a1);
            a2 = fmaf(h1[k + 2], W2[(k + 2) * 64 + tid], a2);
            a3 = fmaf(h1[k + 3], W2[(k + 3) * 64 + tid], a3);
        }
        h2[tid] = fmaxf(((a0 + a1) + (a2 + a3)) + b2[tid], 0.f);
    }
    __syncthreads();
}

// classifier logits on gated row; lg[2] in LDS filled; all threads see lg after return
__device__ __forceinline__ void classify_logits(const float* rS, float* h1, float* h2, float* lg,
                                                const float* W1, const float* b1,
                                                const float* W2, const float* b2,
                                                const float* W3, const float* b3, int tid) {
    mlp_256_64(rS, h1, h2, W1, b1, W2, b2, tid);
    if (tid == 0) {
        float l0 = b3[0], l1 = b3[1];
        for (int k = 0; k < 64; k++) {
            l0 = fmaf(h2[k], W3[2 * k + 0], l0);
            l1 = fmaf(h2[k], W3[2 * k + 1], l1);
        }
        lg[0] = l0; lg[1] = l1;
    }
    __syncthreads();
}

// ---------------- CSR build (deterministic: int atomics + per-node sort) ----------------

__global__ void k_count(const int* __restrict__ dst, int* deg) {
    int e = blockIdx.x * blockDim.x + threadIdx.x;
    if (e < NE) atomicAdd(&deg[dst[e]], 1);
}

__global__ void k_offsets(const int* __restrict__ deg, int* offs, int* fillpos) {
    int c = 0;
    for (int n = 0; n < NN; n++) { offs[n] = c; fillpos[n] = c; c += deg[n]; }
    offs[NN] = c;
}

__global__ void k_fill(const int* __restrict__ dst, int* fillpos, int* elist) {
    int e = blockIdx.x * blockDim.x + threadIdx.x;
    if (e < NE) { int p = atomicAdd(&fillpos[dst[e]], 1); elist[p] = e; }
}

__global__ void k_sort(int* elist, const int* __restrict__ offs) {
    int n = blockIdx.x * blockDim.x + threadIdx.x;
    if (n >= NN) return;
    int lo = offs[n], hi = offs[n + 1];
    for (int a = lo + 1; a < hi; a++) {
        int v = elist[a]; int b = a - 1;
        while (b >= lo && elist[b] > v) { elist[b + 1] = elist[b]; b--; }
        elist[b + 1] = v;
    }
}

// ---------------- message passing ----------------

// H0[e] = [x[src[e]], ea[e]] @ Wi + bi ; Ht = relu(H0)
__global__ void k_edge_init(const float* __restrict__ x, const float* __restrict__ ea,
                            const int* __restrict__ src,
                            const float* __restrict__ Wi, const float* __restrict__ bi,
                            float* __restrict__ H0, float* __restrict__ Ht) {
    __shared__ float in[EB][KIN + 1];
    int e0 = blockIdx.x * EB;
    int h = threadIdx.x;
    for (int j = 0; j < EB; j++) {
        int e = e0 + j; int s = src[e];
        for (int k = h; k < KIN; k += HID)
            in[j][k] = (k < ND) ? x[s * ND + k] : ea[e * BD + (k - ND)];
    }
    __syncthreads();
    float acc[EB];
#pragma unroll
    for (int j = 0; j < EB; j++) acc[j] = 0.f;
    for (int k = 0; k < KIN; k++) {
        float w = Wi[k * HID + h];
#pragma unroll
        for (int j = 0; j < EB; j++) acc[j] = fmaf(in[j][k], w, acc[j]);
    }
    float b = bi[h];
    for (int j = 0; j < EB; j++) {
        float v = acc[j] + b;
        H0[(e0 + j) * HID + h] = v;
        Ht[(e0 + j) * HID + h] = fmaxf(v, 0.f);
    }
}

// agg[n] = sum over incoming edges (fixed ascending order)
__global__ void k_segsum(const float* __restrict__ Ht, const int* __restrict__ elist,
                         const int* __restrict__ offs, float* __restrict__ agg) {
    int n = blockIdx.x; int h = threadIdx.x;
    int lo = offs[n], hi = offs[n + 1];
    float a = 0.f;
    for (int j = lo; j < hi; j++) {
        int e = elist[j];
        a += Ht[e * HID + h];
    }
    agg[n * HID + h] = a;
}

// Ht_out[e] = relu(H0[e] + (agg[src[e]] - Ht_in[rev[e]]) @ Wh + bh)
__global__ void k_edge_update(const float* __restrict__ H0, const float* __restrict__ Htin,
                              const float* __restrict__ agg,
                              const int* __restrict__ src, const int* __restrict__ rev,
                              const float* __restrict__ Wh, const float* __restrict__ bh,
                              float* __restrict__ Htout) {
    __shared__ float M[EB][HID];
    int e0 = blockIdx.x * EB;
    int h = threadIdx.x;
    for (int j = 0; j < EB; j++) {
        int e = e0 + j; int s = src[e]; int r = rev[e];
        M[j][h] = agg[s * HID + h] - Htin[r * HID + h];
    }
    __syncthreads();
    float acc[EB];
#pragma unroll
    for (int j = 0; j < EB; j++) acc[j] = 0.f;
    for (int k = 0; k < HID; k++) {
        float w = Wh[k * HID + h];
#pragma unroll
        for (int j = 0; j < EB; j++) acc[j] = fmaf(M[j][k], w, acc[j]);
    }
    float b = bh[h];
    for (int j = 0; j < EB; j++) {
        int e = e0 + j;
        Htout[e * HID + h] = fmaxf(H0[e * HID + h] + acc[j] + b, 0.f);
    }
}

// E = relu([x, M] @ Wo + bo), M = (rowsum(agg)==0) ? x@Wnt+bnt : agg
__global__ void k_node_embed(const float* __restrict__ x, const float* __restrict__ agg,
                             const float* __restrict__ Wnt, const float* __restrict__ bnt,
                             const float* __restrict__ Wo, const float* __restrict__ bo,
                             float* __restrict__ Emb) {
    __shared__ float xs[ND + 1];
    __shared__ float Ms[HID];
    __shared__ float red[HID];
    int n = blockIdx.x; int h = threadIdx.x;
    for (int k = h; k < ND; k += HID) xs[k] = x[n * ND + k];
    float a = agg[n * HID + h];
    red[h] = a;
    __syncthreads();
    for (int st = 64; st > 0; st >>= 1) { if (h < st) red[h] += red[h + st]; __syncthreads(); }
    float s = red[0];
    __syncthreads();
    float Mh;
    if (s == 0.0f) {
        float t0 = 0.f, t1 = 0.f;
        int k = 0;
        for (; k + 1 < ND; k += 2) {
            t0 = fmaf(xs[k], Wnt[k * HID + h], t0);
            t1 = fmaf(xs[k + 1], Wnt[(k + 1) * HID + h], t1);
        }
        for (; k < ND; k++) t0 = fmaf(xs[k], Wnt[k * HID + h], t0);
        Mh = (t0 + t1) + bnt[h];
    } else {
        Mh = a;
    }
    Ms[h] = Mh;
    __syncthreads();
    float a0 = 0.f, a1 = 0.f;
    int k = 0;
    for (; k + 1 < ND; k += 2) {
        a0 = fmaf(xs[k], Wo[k * HID + h], a0);
        a1 = fmaf(xs[k + 1], Wo[(k + 1) * HID + h], a1);
    }
    for (; k < ND; k++) a0 = fmaf(xs[k], Wo[k * HID + h], a0);
    for (int q = 0; q < HID; q += 2) {
        a0 = fmaf(Ms[q], Wo[(ND + q) * HID + h], a0);
        a1 = fmaf(Ms[q + 1], Wo[(ND + q + 1) * HID + h], a1);
    }
    Emb[n * HID + h] = fmaxf((a0 + a1) + bo[h], 0.f);
}

// ---------------- speculative sequential-scan resolution ----------------

__global__ void k_build_valid(const float* __restrict__ pka, int* validIdx, int* NvP) {
    int c = 0;
    for (int i = 0; i < NN; i++) {
        float v = pka[i];
        if (!(v != v)) { if (c < NN) validIdx[c] = i; c++; }
    }
    *NvP = (c > NVMAX) ? NVMAX : c;
}

// per valid row v: states after k=0..v gates
__global__ void k_chains(const float* __restrict__ Emb, const int* __restrict__ validIdx,
                         const int* __restrict__ NvP,
                         const float* __restrict__ Wg, const float* __restrict__ bg,
                         float* __restrict__ specSt) {
    int v = blockIdx.x;
    if (v >= *NvP) return;
    int tid = threadIdx.x;
    __shared__ float rS[HID];
    int i = validIdx[v];
    rS[tid] = Emb[i * HID + tid];
    __syncthreads();
    specSt[(v * NVMAX + 0) * HID + tid] = rS[tid];
    int kmax = (v < NVMAX - 1) ? v : (NVMAX - 1);
    for (int k = 1; k <= kmax; k++) {
        gate_step(rS, Wg, bg, tid);
        specSt[(v * NVMAX + k) * HID + tid] = rS[tid];
    }
}

// label table for (v, k), k<=v, only where mask==0 (mask>0 fires unconditionally)
__global__ void k_table(const float* __restrict__ specSt, const int* __restrict__ validIdx,
                        const int* __restrict__ NvP, const int* __restrict__ mask,
                        const float* __restrict__ Wc1, const float* __restrict__ bc1,
                        const float* __restrict__ Wc2, const float* __restrict__ bc2,
                        const float* __restrict__ Wc3, const float* __restrict__ bc3,
                        int* __restrict__ labTab) {
    int bid = blockIdx.x;
    int v = bid >> 7, k = bid & (NVMAX - 1);
    if (v >= *NvP || k > v) return;
    int i = validIdx[v];
    if (mask[i] > 0) return;
    __shared__ float rS[HID];
    __shared__ float h1[256];
    __shared__ float h2[64];
    __shared__ float lg[2];
    int tid = threadIdx.x;
    if (tid < HID) rS[tid] = specSt[(v * NVMAX + k) * HID + tid];
    __syncthreads();
    classify_logits(rS, h1, h2, lg, Wc1, bc1, Wc2, bc2, Wc3, bc3, tid);
    if (tid == 0) labTab[v * NVMAX + k] = (lg[1] > lg[0]) ? 1 : 0;
}

__global__ void k_resolve(const int* __restrict__ validIdx, const int* __restrict__ NvP,
                          const int* __restrict__ mask, const int* __restrict__ labTab,
                          int* fireFlag, int* kPref) {
    int Nv = *NvP;
    int k = 0;
    for (int v = 0; v < Nv; v++) {
        int i = validIdx[v];
        int fire = (mask[i] > 0) ? 1 : labTab[v * NVMAX + k];
        fireFlag[i] = fire;
        k += fire;
    }
    int c = 0;
    for (int i = 0; i < NN; i++) { kPref[i] = c; c += fireFlag[i]; }
}

// ---------------- final per-node pass ----------------

__global__ void k_final(const float* __restrict__ Emb, const int* __restrict__ kPref,
                        const int* __restrict__ fireFlag, const int* __restrict__ mask,
                        const float* __restrict__ pka,
                        const float* __restrict__ Wg, const float* __restrict__ bg,
                        const float* __restrict__ Wc1, const float* __restrict__ bc1,
                        const float* __restrict__ Wc2, const float* __restrict__ bc2,
                        const float* __restrict__ Wc3, const float* __restrict__ bc3,
                        const float* __restrict__ Wr1, const float* __restrict__ br1,
                        const float* __restrict__ Wr2, const float* __restrict__ br2,
                        const float* __restrict__ Wr3, const float* __restrict__ br3,
                        float* __restrict__ outLabels, float* __restrict__ outPreds,
                        float* __restrict__ ceArr, float* __restrict__ regArr,
                        float* __restrict__ corArr) {
    __shared__ float rS[HID];
    __shared__ float h1[256];
    __shared__ float h2[64];
    __shared__ float lg[2];
    int i = blockIdx.x; int tid = threadIdx.x;
    if (tid < HID) rS[tid] = Emb[i * HID + tid];
    __syncthreads();
    int kc = kPref[i];
    for (int t = 0; t < kc; t++) gate_step(rS, Wg, bg, tid);

    classify_logits(rS, h1, h2, lg, Wc1, bc1, Wc2, bc2, Wc3, bc3, tid);
    float l0 = lg[0], l1 = lg[1];
    __syncthreads();

    mlp_256_64(rS, h1, h2, Wr1, br1, Wr2, br2, tid);
    if (tid == 0) {
        float pr = br3[0];
        for (int k = 0; k < 64; k++) pr = fmaf(h2[k], Wr3[k], pr);
        float p = sigm(pr);
        p = fminf(fmaxf(p, 0.f), 14.f);

        int label = (l1 > l0) ? 1 : 0;
        int target = (mask[i] > 0) ? 1 : 0;
        float mx = fmaxf(l0, l1);
        float lse = mx + logf(expf(l0 - mx) + expf(l1 - mx));
        float ce = lse - ((target == 1) ? l1 : l0);
        int reg_cond = (label == 1) || (mask[i] > 0);

        outLabels[i] = (float)label;
        outPreds[i] = reg_cond ? p : 0.f;
        ceArr[i] = ce;
        corArr[i] = (label == target) ? 1.f : 0.f;
        if (fireFlag[i]) {
            float d = p - pka[i];
            regArr[i] = d * d;
        } else {
            regArr[i] = 0.f;
        }
    }
}

__global__ void k_loss(const float* __restrict__ ceArr, const float* __restrict__ regArr,
                       const float* __restrict__ corArr, float* __restrict__ out) {
    __shared__ float s[NN];
    int t = threadIdx.x;
    s[t] = ceArr[t]; __syncthreads();
    for (int st = 512; st > 0; st >>= 1) { if (t < st) s[t] += s[t + st]; __syncthreads(); }
    float cls = s[0]; __syncthreads();
    s[t] = regArr[t]; __syncthreads();
    for (int st = 512; st > 0; st >>= 1) { if (t < st) s[t] += s[t + st]; __syncthreads(); }
    float reg = s[0]; __syncthreads();
    s[t] = corArr[t]; __syncthreads();
    for (int st = 512; st > 0; st >>= 1) { if (t < st) s[t] += s[t + st]; __syncthreads(); }
    float cor = s[0];
    if (t == 0) {
        out[0] = cls + reg;
        out[1] = cls;
        out[2] = reg;
        out[3] = cor / (float)NN;
    }
}

// ---------------- launch ----------------

extern "C" void kernel_launch(void* const* d_in, const int* in_sizes, int n_in,
                              void* d_out, int out_size, void* d_ws, size_t ws_size,
                              hipStream_t stream) {
    const float* x    = (const float*)d_in[0];
    const float* ea   = (const float*)d_in[1];
    const float* pka  = (const float*)d_in[2];
    const int*   mask = (const int*)d_in[3];
    const int*   eidx = (const int*)d_in[4];
    const int*   rev  = (const int*)d_in[5];
    const float* Wi  = (const float*)d_in[6];  const float* bi  = (const float*)d_in[7];
    const float* Wh  = (const float*)d_in[8];  const float* bh  = (const float*)d_in[9];
    const float* Wo  = (const float*)d_in[10]; const float* bo  = (const float*)d_in[11];
    const float* Wnt = (const float*)d_in[12]; const float* bnt = (const float*)d_in[13];
    const float* Wc1 = (const float*)d_in[14]; const float* bc1 = (const float*)d_in[15];
    const float* Wc2 = (const float*)d_in[16]; const float* bc2 = (const float*)d_in[17];
    const float* Wc3 = (const float*)d_in[18]; const float* bc3 = (const float*)d_in[19];
    const float* Wr1 = (const float*)d_in[20]; const float* br1 = (const float*)d_in[21];
    const float* Wr2 = (const float*)d_in[22]; const float* br2 = (const float*)d_in[23];
    const float* Wr3 = (const float*)d_in[24]; const float* br3 = (const float*)d_in[25];
    const float* Wg  = (const float*)d_in[26]; const float* bg  = (const float*)d_in[27];

    const int* src = eidx;
    const int* dst = eidx + NE;

    char* w = (char*)d_ws;
    auto alloc = [&](size_t bytes) -> void* {
        void* p = (void*)w;
        w += ((bytes + 255) / 256) * 256;
        return p;
    };
    float* H0   = (float*)alloc((size_t)NE * HID * 4);
    float* HtA  = (float*)alloc((size_t)NE * HID * 4);
    float* HtB  = (float*)alloc((size_t)NE * HID * 4);
    float* agg  = (float*)alloc((size_t)NN * HID * 4);
    float* Emb  = (float*)alloc((size_t)NN * HID * 4);
    int* deg     = (int*)alloc(NN * 4);
    int* offs    = (int*)alloc((NN + 1) * 4);
    int* fillpos = (int*)alloc(NN * 4);
    int* elist   = (int*)alloc(NE * 4);
    int* validIdx= (int*)alloc(NN * 4);
    int* NvP     = (int*)alloc(16);
    int* fireFlag= (int*)alloc(NN * 4);
    int* kPref   = (int*)alloc(NN * 4);
    float* specSt= (float*)alloc((size_t)NVMAX * NVMAX * HID * 4);
    int* labTab  = (int*)alloc(NVMAX * NVMAX * 4);
    float* ceArr = (float*)alloc(NN * 4);
    float* regArr= (float*)alloc(NN * 4);
    float* corArr= (float*)alloc(NN * 4);

    float* outF = (float*)d_out;  // [labels 1024][preds 1024][loss 4]

    hipMemsetAsync(deg, 0, NN * 4, stream);
    hipMemsetAsync(fireFlag, 0, NN * 4, stream);

    k_count<<<NE / 256, 256, 0, stream>>>(dst, deg);
    k_offsets<<<1, 1, 0, stream>>>(deg, offs, fillpos);
    k_fill<<<NE / 256, 256, 0, stream>>>(dst, fillpos, elist);
    k_sort<<<(NN + 255) / 256, 256, 0, stream>>>(elist, offs);

    k_edge_init<<<NE / EB, HID, 0, stream>>>(x, ea, src, Wi, bi, H0, HtA);
    k_segsum<<<NN, HID, 0, stream>>>(HtA, elist, offs, agg);
    k_edge_update<<<NE / EB, HID, 0, stream>>>(H0, HtA, agg, src, rev, Wh, bh, HtB);
    k_segsum<<<NN, HID, 0, stream>>>(HtB, elist, offs, agg);
    k_edge_update<<<NE / EB, HID, 0, stream>>>(H0, HtB, agg, src, rev, Wh, bh, HtA);
    k_segsum<<<NN, HID, 0, stream>>>(HtA, elist, offs, agg);
    k_node_embed<<<NN, HID, 0, stream>>>(x, agg, Wnt, bnt, Wo, bo, Emb);

    k_build_valid<<<1, 1, 0, stream>>>(pka, validIdx, NvP);
    k_chains<<<NVMAX, HID, 0, stream>>>(Emb, validIdx, NvP, Wg, bg, specSt);
    k_table<<<NVMAX * NVMAX, 256, 0, stream>>>(specSt, validIdx, NvP, mask,
                                               Wc1, bc1, Wc2, bc2, Wc3, bc3, labTab);
    k_resolve<<<1, 1, 0, stream>>>(validIdx, NvP, mask, labTab, fireFlag, kPref);

    k_final<<<NN, 256, 0, stream>>>(Emb, kPref, fireFlag, mask, pka,
                                    Wg, bg, Wc1, bc1, Wc2, bc2, Wc3, bc3,
                                    Wr1, br1, Wr2, br2, Wr3, br3,
                                    outF, outF + NN, ceArr, regArr, corArr);
    k_loss<<<1, NN, 0, stream>>>(ceArr, regArr, corArr, outF + 2 * NN);
}

// Round 2
// 349.887 us; speedup vs baseline: 2.0298x; 2.0298x over previous
//
#include <hip/hip_runtime.h>

#define NN   1024
#define NE   16384
#define HID  128
#define ND   133
#define BD   14
#define KIN  147   // ND + BD
#define NVMAX 128
#define EB   8     // edges per block in edge kernels
#define JF   4     // nodes per block in final pass
#define JT   8     // pairs per block in table pass
#define MAXPAIRS (NVMAX * (NVMAX + 1) / 2)

// ---------------- shared device math ----------------

__device__ __forceinline__ float sigm(float x) { return 1.0f / (1.0f + expf(-x)); }

// ---------------- CSR build (deterministic: int atomics + per-node sort) ----------------

__global__ void k_count(const int* __restrict__ dst, int* deg) {
    int e = blockIdx.x * blockDim.x + threadIdx.x;
    if (e < NE) atomicAdd(&deg[dst[e]], 1);
}

// parallel exclusive scan of degrees (1 block, 1024 threads)
__global__ void k_scan_offsets(const int* __restrict__ deg, int* offs, int* fillpos) {
    __shared__ int s[NN];
    int t = threadIdx.x;
    int d0 = deg[t];
    s[t] = d0;
    __syncthreads();
    for (int st = 1; st < NN; st <<= 1) {
        int v = (t >= st) ? s[t - st] : 0;
        __syncthreads();
        s[t] += v;
        __syncthreads();
    }
    int excl = s[t] - d0;
    offs[t] = excl;
    fillpos[t] = excl;
    if (t == NN - 1) offs[NN] = s[t];
}

__global__ void k_fill(const int* __restrict__ dst, int* fillpos, int* elist) {
    int e = blockIdx.x * blockDim.x + threadIdx.x;
    if (e < NE) { int p = atomicAdd(&fillpos[dst[e]], 1); elist[p] = e; }
}

__global__ void k_sort(int* elist, const int* __restrict__ offs) {
    int n = blockIdx.x * blockDim.x + threadIdx.x;
    if (n >= NN) return;
    int lo = offs[n], hi = offs[n + 1];
    for (int a = lo + 1; a < hi; a++) {
        int v = elist[a]; int b = a - 1;
        while (b >= lo && elist[b] > v) { elist[b + 1] = elist[b]; b--; }
        elist[b + 1] = v;
    }
}

// ---------------- message passing ----------------

__global__ void k_edge_init(const float* __restrict__ x, const float* __restrict__ ea,
                            const int* __restrict__ src,
                            const float* __restrict__ Wi, const float* __restrict__ bi,
                            float* __restrict__ H0, float* __restrict__ Ht) {
    __shared__ float in[EB][KIN + 1];
    int e0 = blockIdx.x * EB;
    int h = threadIdx.x;
    for (int j = 0; j < EB; j++) {
        int e = e0 + j; int s = src[e];
        for (int k = h; k < KIN; k += HID)
            in[j][k] = (k < ND) ? x[s * ND + k] : ea[e * BD + (k - ND)];
    }
    __syncthreads();
    float acc[EB];
#pragma unroll
    for (int j = 0; j < EB; j++) acc[j] = 0.f;
    for (int k = 0; k < KIN; k++) {
        float w = Wi[k * HID + h];
#pragma unroll
        for (int j = 0; j < EB; j++) acc[j] = fmaf(in[j][k], w, acc[j]);
    }
    float b = bi[h];
    for (int j = 0; j < EB; j++) {
        float v = acc[j] + b;
        H0[(e0 + j) * HID + h] = v;
        Ht[(e0 + j) * HID + h] = fmaxf(v, 0.f);
    }
}

__global__ void k_segsum(const float* __restrict__ Ht, const int* __restrict__ elist,
                         const int* __restrict__ offs, float* __restrict__ agg) {
    int n = blockIdx.x; int h = threadIdx.x;
    int lo = offs[n], hi = offs[n + 1];
    float a = 0.f;
    for (int j = lo; j < hi; j++) {
        int e = elist[j];
        a += Ht[e * HID + h];
    }
    agg[n * HID + h] = a;
}

__global__ void k_edge_update(const float* __restrict__ H0, const float* __restrict__ Htin,
                              const float* __restrict__ agg,
                              const int* __restrict__ src, const int* __restrict__ rev,
                              const float* __restrict__ Wh, const float* __restrict__ bh,
                              float* __restrict__ Htout) {
    __shared__ float M[EB][HID];
    int e0 = blockIdx.x * EB;
    int h = threadIdx.x;
    for (int j = 0; j < EB; j++) {
        int e = e0 + j; int s = src[e]; int r = rev[e];
        M[j][h] = agg[s * HID + h] - Htin[r * HID + h];
    }
    __syncthreads();
    float acc[EB];
#pragma unroll
    for (int j = 0; j < EB; j++) acc[j] = 0.f;
    for (int k = 0; k < HID; k++) {
        float w = Wh[k * HID + h];
#pragma unroll
        for (int j = 0; j < EB; j++) acc[j] = fmaf(M[j][k], w, acc[j]);
    }
    float b = bh[h];
    for (int j = 0; j < EB; j++) {
        int e = e0 + j;
        Htout[e * HID + h] = fmaxf(H0[e * HID + h] + acc[j] + b, 0.f);
    }
}

__global__ void k_node_embed(const float* __restrict__ x, const float* __restrict__ agg,
                             const float* __restrict__ Wnt, const float* __restrict__ bnt,
                             const float* __restrict__ Wo, const float* __restrict__ bo,
                             float* __restrict__ Emb) {
    __shared__ float xs[ND + 1];
    __shared__ float Ms[HID];
    __shared__ float red[HID];
    int n = blockIdx.x; int h = threadIdx.x;
    for (int k = h; k < ND; k += HID) xs[k] = x[n * ND + k];
    float a = agg[n * HID + h];
    red[h] = a;
    __syncthreads();
    for (int st = 64; st > 0; st >>= 1) { if (h < st) red[h] += red[h + st]; __syncthreads(); }
    float s = red[0];
    __syncthreads();
    float Mh;
    if (s == 0.0f) {
        float t0 = 0.f, t1 = 0.f;
        int k = 0;
        for (; k + 1 < ND; k += 2) {
            t0 = fmaf(xs[k], Wnt[k * HID + h], t0);
            t1 = fmaf(xs[k + 1], Wnt[(k + 1) * HID + h], t1);
        }
        for (; k < ND; k++) t0 = fmaf(xs[k], Wnt[k * HID + h], t0);
        Mh = (t0 + t1) + bnt[h];
    } else {
        Mh = a;
    }
    Ms[h] = Mh;
    __syncthreads();
    float a0 = 0.f, a1 = 0.f;
    int k = 0;
    for (; k + 1 < ND; k += 2) {
        a0 = fmaf(xs[k], Wo[k * HID + h], a0);
        a1 = fmaf(xs[k + 1], Wo[(k + 1) * HID + h], a1);
    }
    for (; k < ND; k++) a0 = fmaf(xs[k], Wo[k * HID + h], a0);
    for (int q = 0; q < HID; q += 2) {
        a0 = fmaf(Ms[q], Wo[(ND + q) * HID + h], a0);
        a1 = fmaf(Ms[q + 1], Wo[(ND + q + 1) * HID + h], a1);
    }
    Emb[n * HID + h] = fmaxf((a0 + a1) + bo[h], 0.f);
}

// ---------------- valid-node compaction (1 block, 1024 threads) ----------------

__global__ void k_build_valid2(const float* __restrict__ pka, int* validIdx, int* NvP, int* vpos) {
    __shared__ int s[NN];
    int t = threadIdx.x;
    float v = pka[t];
    int f = (v == v) ? 1 : 0;   // !isnan
    s[t] = f;
    __syncthreads();
    for (int st = 1; st < NN; st <<= 1) {
        int u = (t >= st) ? s[t - st] : 0;
        __syncthreads();
        s[t] += u;
        __syncthreads();
    }
    int incl = s[t];
    int pos = incl - f;
    int ok = (f && pos < NVMAX) ? 1 : 0;
    vpos[t] = ok ? pos : -1;
    if (ok) validIdx[pos] = t;
    if (t == NN - 1) *NvP = (incl > NVMAX) ? NVMAX : incl;
}

// ---------------- speculative gate chains (LDS-staged Wg) ----------------

__global__ void k_chains2(const float* __restrict__ Emb, const int* __restrict__ validIdx,
                          const int* __restrict__ NvP,
                          const float* __restrict__ Wg, const float* __restrict__ bg,
                          float* __restrict__ specSt) {
    int v = blockIdx.x;
    int Nv = *NvP;
    if (v >= Nv) return;
    __shared__ float WgS[HID * HID];
    __shared__ float rS[HID];
    int tid = threadIdx.x;  // 128 threads
    const float4* Wg4 = (const float4*)Wg;
    float4* Ws4 = (float4*)WgS;
    for (int idx = tid; idx < HID * HID / 4; idx += HID) Ws4[idx] = Wg4[idx];
    int i = validIdx[v];
    rS[tid] = Emb[i * HID + tid];
    float bgc = bg[tid];
    __syncthreads();
    specSt[(v * NVMAX + 0) * HID + tid] = rS[tid];
    int kmax = (v < NVMAX - 1) ? v : (NVMAX - 1);
    for (int k = 1; k <= kmax; k++) {
        float t0 = 0.f, t1 = 0.f, t2 = 0.f, t3 = 0.f;
        for (int q = 0; q < HID; q += 4) {
            t0 = fmaf(rS[q + 0], WgS[(q + 0) * HID + tid], t0);
            t1 = fmaf(rS[q + 1], WgS[(q + 1) * HID + tid], t1);
            t2 = fmaf(rS[q + 2], WgS[(q + 2) * HID + tid], t2);
            t3 = fmaf(rS[q + 3], WgS[(q + 3) * HID + tid], t3);
        }
        float g = 1.0f - sigm(((t0 + t1) + (t2 + t3)) + bgc);
        __syncthreads();
        rS[tid] *= g;
        specSt[(v * NVMAX + k) * HID + tid] = rS[tid];
        __syncthreads();
    }
}

// ---------------- active-pair compaction ----------------

__global__ void k_pairs(const int* __restrict__ NvP, const int* __restrict__ mask,
                        const int* __restrict__ validIdx, int* pairCnt, int* pairList) {
    int t = blockIdx.x * blockDim.x + threadIdx.x;  // over NVMAX*NVMAX
    int v = t >> 7, k = t & (NVMAX - 1);
    int Nv = *NvP;
    if (v < Nv && k <= v && mask[validIdx[v]] == 0) {
        int p = atomicAdd(pairCnt, 1);
        pairList[p] = t;
    }
}

// ---------------- batched classifier table (JT pairs per block) ----------------

__global__ void k_table2(const float* __restrict__ specSt, const int* __restrict__ pairList,
                         const int* __restrict__ pairCnt,
                         const float* __restrict__ Wc1, const float* __restrict__ bc1,
                         const float* __restrict__ Wc2, const float* __restrict__ bc2,
                         const float* __restrict__ Wc3, const float* __restrict__ bc3,
                         int* __restrict__ labTab) {
    int cnt = *pairCnt;
    int base = blockIdx.x * JT;
    if (base >= cnt) return;
    int nj = cnt - base; if (nj > JT) nj = JT;
    __shared__ float rS[JT][HID];
    __shared__ float h1S[JT][256];
    __shared__ float h2S[JT][64];
    __shared__ int plS[JT];
    int tid = threadIdx.x;  // 256
    if (tid < JT) plS[tid] = (tid < nj) ? pairList[base + tid] : 0;
    __syncthreads();
    for (int idx = tid; idx < JT * HID; idx += 256) {
        int j = idx >> 7, k = idx & (HID - 1);
        rS[j][k] = (j < nj) ? specSt[plS[j] * HID + k] : 0.f;
    }
    __syncthreads();
    // layer 1: 128 -> 256
    float a[JT];
#pragma unroll
    for (int j = 0; j < JT; j++) a[j] = 0.f;
    for (int k = 0; k < HID; k++) {
        float w = Wc1[k * 256 + tid];
#pragma unroll
        for (int j = 0; j < JT; j++) a[j] = fmaf(rS[j][k], w, a[j]);
    }
    float b1 = bc1[tid];
#pragma unroll
    for (int j = 0; j < JT; j++) h1S[j][tid] = fmaxf(a[j] + b1, 0.f);
    __syncthreads();
    // layer 2: 256 -> 64; 4 groups x 64 cols, each group handles 2 pairs
    {
        int col = tid & 63, g2 = (tid >> 6) * 2;
        float b0 = 0.f, bb1 = 0.f;
        for (int k = 0; k < 256; k++) {
            float w = Wc2[k * 64 + col];
            b0 = fmaf(h1S[g2][k], w, b0);
            bb1 = fmaf(h1S[g2 + 1][k], w, bb1);
        }
        float b2 = bc2[col];
        h2S[g2][col] = fmaxf(b0 + b2, 0.f);
        h2S[g2 + 1][col] = fmaxf(bb1 + b2, 0.f);
    }
    __syncthreads();
    // layer 3 + decision
    if (tid < nj) {
        float l0 = bc3[0], l1 = bc3[1];
        for (int k = 0; k < 64; k++) {
            float h = h2S[tid][k];
            l0 = fmaf(h, Wc3[2 * k + 0], l0);
            l1 = fmaf(h, Wc3[2 * k + 1], l1);
        }
        labTab[plS[tid]] = (l1 > l0) ? 1 : 0;
    }
}

// ---------------- fast resolve (1 block, 1024 threads, LDS walk + scan) ----------------

__global__ void k_resolve2(const int* __restrict__ validIdx, const int* __restrict__ NvP,
                           const int* __restrict__ mask, const int* __restrict__ labTab,
                           int* fireFlag, int* kPref) {
    __shared__ int vIdxS[NVMAX];
    __shared__ int maskS[NVMAX];
    __shared__ int labS[NVMAX * NVMAX];
    __shared__ int fireS[NN];
    __shared__ int scanS[NN];
    int t = threadIdx.x;
    int Nv = *NvP;
    if (t < NVMAX) {
        int vi = (t < Nv) ? validIdx[t] : 0;
        vIdxS[t] = vi;
        maskS[t] = (t < Nv) ? mask[vi] : 0;
    }
    fireS[t] = 0;
    for (int idx = t; idx < Nv * NVMAX; idx += NN) labS[idx] = labTab[idx];
    __syncthreads();
    if (t == 0) {
        int k = 0;
        for (int v = 0; v < Nv; v++) {
            int fire = (maskS[v] > 0) ? 1 : labS[v * NVMAX + k];
            fireS[vIdxS[v]] = fire;
            k += fire;
        }
    }
    __syncthreads();
    int f0 = fireS[t];
    scanS[t] = f0;
    __syncthreads();
    for (int st = 1; st < NN; st <<= 1) {
        int u = (t >= st) ? scanS[t - st] : 0;
        __syncthreads();
        scanS[t] += u;
        __syncthreads();
    }
    kPref[t] = scanS[t] - f0;
    fireFlag[t] = f0;
}

// ---------------- fused final pass: JF nodes per block ----------------

__global__ void __launch_bounds__(256)
k_final2(const float* __restrict__ Emb, const int* __restrict__ kPref,
         const int* __restrict__ fireFlag, const int* __restrict__ mask,
         const float* __restrict__ pka, const int* __restrict__ vpos,
         const int* __restrict__ labTab,
         const float* __restrict__ Wg, const float* __restrict__ bg,
         const float* __restrict__ Wc1, const float* __restrict__ bc1,
         const float* __restrict__ Wc2, const float* __restrict__ bc2,
         const float* __restrict__ Wc3, const float* __restrict__ bc3,
         const float* __restrict__ Wr1, const float* __restrict__ br1,
         const float* __restrict__ Wr2, const float* __restrict__ br2,
         const float* __restrict__ Wr3, const float* __restrict__ br3,
         float* __restrict__ outLabels, float* __restrict__ outPreds,
         float* __restrict__ ceArr, float* __restrict__ regArr,
         float* __restrict__ corArr) {
    __shared__ float WgS[HID * HID];       // 64 KB
    __shared__ float rS[JF][HID];
    __shared__ float h1S[JF][256];
    __shared__ float h2S[JF][64];
    __shared__ float lgS[JF][2];
    __shared__ float prS[JF];
    __shared__ int kcS[JF];
    int tid = threadIdx.x;  // 256
    int i0 = blockIdx.x * JF;

    const float4* Wg4 = (const float4*)Wg;
    float4* Ws4 = (float4*)WgS;
    for (int idx = tid; idx < HID * HID / 4; idx += 256) Ws4[idx] = Wg4[idx];
    if (tid < HID) {
#pragma unroll
        for (int j = 0; j < JF; j++) rS[j][tid] = Emb[(i0 + j) * HID + tid];
    }
    if (tid < JF) kcS[tid] = kPref[i0 + tid];
    __syncthreads();
    int kc[JF]; int maxkc = 0;
#pragma unroll
    for (int j = 0; j < JF; j++) { kc[j] = kcS[j]; if (kc[j] > maxkc) maxkc = kc[j]; }

    // ---- gate rounds: each thread handles (col, 2 nodes of its slot) ----
    int col = tid & (HID - 1);
    int slot = tid >> 7;           // 0 -> nodes {0,1}, 1 -> nodes {2,3}
    int j0 = slot * 2, j1 = slot * 2 + 1;
    float bgc = bg[col];
    for (int t = 0; t < maxkc; t++) {
        float a00 = 0.f, a01 = 0.f, a02 = 0.f, a03 = 0.f;
        float a10 = 0.f, a11 = 0.f, a12 = 0.f, a13 = 0.f;
        for (int q = 0; q < HID; q += 4) {
            float w0 = WgS[(q + 0) * HID + col];
            float w1 = WgS[(q + 1) * HID + col];
            float w2 = WgS[(q + 2) * HID + col];
            float w3 = WgS[(q + 3) * HID + col];
            a00 = fmaf(rS[j0][q + 0], w0, a00);
            a01 = fmaf(rS[j0][q + 1], w1, a01);
            a02 = fmaf(rS[j0][q + 2], w2, a02);
            a03 = fmaf(rS[j0][q + 3], w3, a03);
            a10 = fmaf(rS[j1][q + 0], w0, a10);
            a11 = fmaf(rS[j1][q + 1], w1, a11);
            a12 = fmaf(rS[j1][q + 2], w2, a12);
            a13 = fmaf(rS[j1][q + 3], w3, a13);
        }
        float g0 = 1.0f - sigm(((a00 + a01) + (a02 + a03)) + bgc);
        float g1 = 1.0f - sigm(((a10 + a11) + (a12 + a13)) + bgc);
        __syncthreads();
        if (t < kc[j0]) rS[j0][col] *= g0;
        if (t < kc[j1]) rS[j1][col] *= g1;
        __syncthreads();
    }

    // ---- classifier: layer1 128->256 ----
    {
        float a[JF];
#pragma unroll
        for (int j = 0; j < JF; j++) a[j] = 0.f;
        for (int k = 0; k < HID; k++) {
            float w = Wc1[k * 256 + tid];
#pragma unroll
            for (int j = 0; j < JF; j++) a[j] = fmaf(rS[j][k], w, a[j]);
        }
        float b = bc1[tid];
#pragma unroll
        for (int j = 0; j < JF; j++) h1S[j][tid] = fmaxf(a[j] + b, 0.f);
    }
    __syncthreads();
    // layer2 256->64: 4 groups of 64 cols, group handles node j=group
    {
        int c2 = tid & 63, j = tid >> 6;
        float acc = 0.f;
        for (int k = 0; k < 256; k++) acc = fmaf(h1S[j][k], Wc2[k * 64 + c2], acc);
        h2S[j][c2] = fmaxf(acc + bc2[c2], 0.f);
    }
    __syncthreads();
    // layer3 64->2
    if (tid < 2 * JF) {
        int j = tid >> 1, c = tid & 1;
        float l = bc3[c];
        for (int k = 0; k < 64; k++) l = fmaf(h2S[j][k], Wc3[2 * k + c], l);
        lgS[j][c] = l;
    }
    __syncthreads();

    // ---- regressor: layer1 ----
    {
        float a[JF];
#pragma unroll
        for (int j = 0; j < JF; j++) a[j] = 0.f;
        for (int k = 0; k < HID; k++) {
            float w = Wr1[k * 256 + tid];
#pragma unroll
            for (int j = 0; j < JF; j++) a[j] = fmaf(rS[j][k], w, a[j]);
        }
        float b = br1[tid];
#pragma unroll
        for (int j = 0; j < JF; j++) h1S[j][tid] = fmaxf(a[j] + b, 0.f);
    }
    __syncthreads();
    {
        int c2 = tid & 63, j = tid >> 6;
        float acc = 0.f;
        for (int k = 0; k < 256; k++) acc = fmaf(h1S[j][k], Wr2[k * 64 + c2], acc);
        h2S[j][c2] = fmaxf(acc + br2[c2], 0.f);
    }
    __syncthreads();
    if (tid < JF) {
        float pr = br3[0];
        for (int k = 0; k < 64; k++) pr = fmaf(h2S[tid][k], Wr3[k], pr);
        prS[tid] = pr;
    }
    __syncthreads();

    // ---- per-node outputs ----
    if (tid < JF) {
        int j = tid, i = i0 + j;
        float l0 = lgS[j][0], l1 = lgS[j][1];
        int compLab = (l1 > l0) ? 1 : 0;
        int vp = vpos[i];
        int label = (vp >= 0 && mask[i] == 0) ? labTab[vp * NVMAX + kc[j]] : compLab;
        int target = (mask[i] > 0) ? 1 : 0;
        float mx = fmaxf(l0, l1);
        float lse = mx + logf(expf(l0 - mx) + expf(l1 - mx));
        float ce = lse - ((target == 1) ? l1 : l0);
        int reg_cond = (label == 1) || (mask[i] > 0);
        float p = sigm(prS[j]);
        p = fminf(fmaxf(p, 0.f), 14.f);
        outLabels[i] = (float)label;
        outPreds[i] = reg_cond ? p : 0.f;
        ceArr[i] = ce;
        corArr[i] = (label == target) ? 1.f : 0.f;
        if (fireFlag[i]) {
            float d = p - pka[i];
            regArr[i] = d * d;
        } else {
            regArr[i] = 0.f;
        }
    }
}

__global__ void k_loss(const float* __restrict__ ceArr, const float* __restrict__ regArr,
                       const float* __restrict__ corArr, float* __restrict__ out) {
    __shared__ float s[NN];
    int t = threadIdx.x;
    s[t] = ceArr[t]; __syncthreads();
    for (int st = 512; st > 0; st >>= 1) { if (t < st) s[t] += s[t + st]; __syncthreads(); }
    float cls = s[0]; __syncthreads();
    s[t] = regArr[t]; __syncthreads();
    for (int st = 512; st > 0; st >>= 1) { if (t < st) s[t] += s[t + st]; __syncthreads(); }
    float reg = s[0]; __syncthreads();
    s[t] = corArr[t]; __syncthreads();
    for (int st = 512; st > 0; st >>= 1) { if (t < st) s[t] += s[t + st]; __syncthreads(); }
    float cor = s[0];
    if (t == 0) {
        out[0] = cls + reg;
        out[1] = cls;
        out[2] = reg;
        out[3] = cor / (float)NN;
    }
}

// ---------------- launch ----------------

extern "C" void kernel_launch(void* const* d_in, const int* in_sizes, int n_in,
                              void* d_out, int out_size, void* d_ws, size_t ws_size,
                              hipStream_t stream) {
    const float* x    = (const float*)d_in[0];
    const float* ea   = (const float*)d_in[1];
    const float* pka  = (const float*)d_in[2];
    const int*   mask = (const int*)d_in[3];
    const int*   eidx = (const int*)d_in[4];
    const int*   rev  = (const int*)d_in[5];
    const float* Wi  = (const float*)d_in[6];  const float* bi  = (const float*)d_in[7];
    const float* Wh  = (const float*)d_in[8];  const float* bh  = (const float*)d_in[9];
    const float* Wo  = (const float*)d_in[10]; const float* bo  = (const float*)d_in[11];
    const float* Wnt = (const float*)d_in[12]; const float* bnt = (const float*)d_in[13];
    const float* Wc1 = (const float*)d_in[14]; const float* bc1 = (const float*)d_in[15];
    const float* Wc2 = (const float*)d_in[16]; const float* bc2 = (const float*)d_in[17];
    const float* Wc3 = (const float*)d_in[18]; const float* bc3 = (const float*)d_in[19];
    const float* Wr1 = (const float*)d_in[20]; const float* br1 = (const float*)d_in[21];
    const float* Wr2 = (const float*)d_in[22]; const float* br2 = (const float*)d_in[23];
    const float* Wr3 = (const float*)d_in[24]; const float* br3 = (const float*)d_in[25];
    const float* Wg  = (const float*)d_in[26]; const float* bg  = (const float*)d_in[27];

    const int* src = eidx;
    const int* dst = eidx + NE;

    char* w = (char*)d_ws;
    auto alloc = [&](size_t bytes) -> void* {
        void* p = (void*)w;
        w += ((bytes + 255) / 256) * 256;
        return p;
    };
    float* H0   = (float*)alloc((size_t)NE * HID * 4);
    float* HtA  = (float*)alloc((size_t)NE * HID * 4);
    float* HtB  = (float*)alloc((size_t)NE * HID * 4);
    float* agg  = (float*)alloc((size_t)NN * HID * 4);
    float* Emb  = (float*)alloc((size_t)NN * HID * 4);
    int* deg     = (int*)alloc(NN * 4);
    int* offs    = (int*)alloc((NN + 1) * 4);
    int* fillpos = (int*)alloc(NN * 4);
    int* elist   = (int*)alloc(NE * 4);
    int* validIdx= (int*)alloc(NVMAX * 4);
    int* NvP     = (int*)alloc(16);
    int* vpos    = (int*)alloc(NN * 4);
    int* fireFlag= (int*)alloc(NN * 4);
    int* kPref   = (int*)alloc(NN * 4);
    float* specSt= (float*)alloc((size_t)NVMAX * NVMAX * HID * 4);
    int* labTab  = (int*)alloc(NVMAX * NVMAX * 4);
    int* pairCnt = (int*)alloc(16);
    int* pairList= (int*)alloc(MAXPAIRS * 4);
    float* ceArr = (float*)alloc(NN * 4);
    float* regArr= (float*)alloc(NN * 4);
    float* corArr= (float*)alloc(NN * 4);

    float* outF = (float*)d_out;  // [labels 1024][preds 1024][loss 4]

    hipMemsetAsync(deg, 0, NN * 4, stream);
    hipMemsetAsync(pairCnt, 0, 4, stream);

    k_count<<<NE / 256, 256, 0, stream>>>(dst, deg);
    k_scan_offsets<<<1, NN, 0, stream>>>(deg, offs, fillpos);
    k_fill<<<NE / 256, 256, 0, stream>>>(dst, fillpos, elist);
    k_sort<<<(NN + 255) / 256, 256, 0, stream>>>(elist, offs);

    k_edge_init<<<NE / EB, HID, 0, stream>>>(x, ea, src, Wi, bi, H0, HtA);
    k_segsum<<<NN, HID, 0, stream>>>(HtA, elist, offs, agg);
    k_edge_update<<<NE / EB, HID, 0, stream>>>(H0, HtA, agg, src, rev, Wh, bh, HtB);
    k_segsum<<<NN, HID, 0, stream>>>(HtB, elist, offs, agg);
    k_edge_update<<<NE / EB, HID, 0, stream>>>(H0, HtB, agg, src, rev, Wh, bh, HtA);
    k_segsum<<<NN, HID, 0, stream>>>(HtA, elist, offs, agg);
    k_node_embed<<<NN, HID, 0, stream>>>(x, agg, Wnt, bnt, Wo, bo, Emb);

    k_build_valid2<<<1, NN, 0, stream>>>(pka, validIdx, NvP, vpos);
    k_chains2<<<NVMAX, HID, 0, stream>>>(Emb, validIdx, NvP, Wg, bg, specSt);
    k_pairs<<<(NVMAX * NVMAX) / 256, 256, 0, stream>>>(NvP, mask, validIdx, pairCnt, pairList);
    k_table2<<<(MAXPAIRS + JT - 1) / JT, 256, 0, stream>>>(specSt, pairList, pairCnt,
                                                           Wc1, bc1, Wc2, bc2, Wc3, bc3, labTab);
    k_resolve2<<<1, NN, 0, stream>>>(validIdx, NvP, mask, labTab, fireFlag, kPref);

    k_final2<<<NN / JF, 256, 0, stream>>>(Emb, kPref, fireFlag, mask, pka, vpos, labTab,
                                          Wg, bg, Wc1, bc1, Wc2, bc2, Wc3, bc3,
                                          Wr1, br1, Wr2, br2, Wr3, br3,
                                          outF, outF + NN, ceArr, regArr, corArr);
    k_loss<<<1, NN, 0, stream>>>(ceArr, regArr, corArr, outF + 2 * NN);
}

// Round 3
// 296.184 us; speedup vs baseline: 2.3979x; 1.1813x over previous
//
#include <hip/hip_runtime.h>

#define NN   1024
#define NE   16384
#define HID  128
#define ND   133
#define BD   14
#define KIN  147   // ND + BD
#define NVMAX 128
#define EB   8     // edges per block in edge kernels
#define JF   4     // nodes per block in final pass
#define JT   8     // pairs per block in table pass
#define MAXPAIRS (NVMAX * (NVMAX + 1) / 2)

// ---------------- shared device math ----------------

__device__ __forceinline__ float sigm(float x) { return 1.0f / (1.0f + expf(-x)); }

// ---------------- CSR build (deterministic: int atomics + per-node sort) ----------------

__global__ void k_count(const int* __restrict__ dst, int* deg) {
    int e = blockIdx.x * blockDim.x + threadIdx.x;
    if (e < NE) atomicAdd(&deg[dst[e]], 1);
}

// parallel exclusive scan of degrees (1 block, 1024 threads)
__global__ void k_scan_offsets(const int* __restrict__ deg, int* offs, int* fillpos) {
    __shared__ int s[NN];
    int t = threadIdx.x;
    int d0 = deg[t];
    s[t] = d0;
    __syncthreads();
    for (int st = 1; st < NN; st <<= 1) {
        int v = (t >= st) ? s[t - st] : 0;
        __syncthreads();
        s[t] += v;
        __syncthreads();
    }
    int excl = s[t] - d0;
    offs[t] = excl;
    fillpos[t] = excl;
    if (t == NN - 1) offs[NN] = s[t];
}

__global__ void k_fill(const int* __restrict__ dst, int* fillpos, int* elist) {
    int e = blockIdx.x * blockDim.x + threadIdx.x;
    if (e < NE) { int p = atomicAdd(&fillpos[dst[e]], 1); elist[p] = e; }
}

__global__ void k_sort(int* elist, const int* __restrict__ offs) {
    int n = blockIdx.x * blockDim.x + threadIdx.x;
    if (n >= NN) return;
    int lo = offs[n], hi = offs[n + 1];
    for (int a = lo + 1; a < hi; a++) {
        int v = elist[a]; int b = a - 1;
        while (b >= lo && elist[b] > v) { elist[b + 1] = elist[b]; b--; }
        elist[b + 1] = v;
    }
}

// ---------------- message passing ----------------

__global__ void k_edge_init(const float* __restrict__ x, const float* __restrict__ ea,
                            const int* __restrict__ src,
                            const float* __restrict__ Wi, const float* __restrict__ bi,
                            float* __restrict__ H0, float* __restrict__ Ht) {
    __shared__ float in[EB][KIN + 1];
    int e0 = blockIdx.x * EB;
    int h = threadIdx.x;
    for (int j = 0; j < EB; j++) {
        int e = e0 + j; int s = src[e];
        for (int k = h; k < KIN; k += HID)
            in[j][k] = (k < ND) ? x[s * ND + k] : ea[e * BD + (k - ND)];
    }
    __syncthreads();
    float acc[EB];
#pragma unroll
    for (int j = 0; j < EB; j++) acc[j] = 0.f;
    for (int k = 0; k < KIN; k++) {
        float w = Wi[k * HID + h];
#pragma unroll
        for (int j = 0; j < EB; j++) acc[j] = fmaf(in[j][k], w, acc[j]);
    }
    float b = bi[h];
    for (int j = 0; j < EB; j++) {
        float v = acc[j] + b;
        H0[(e0 + j) * HID + h] = v;
        Ht[(e0 + j) * HID + h] = fmaxf(v, 0.f);
    }
}

__global__ void k_segsum(const float* __restrict__ Ht, const int* __restrict__ elist,
                         const int* __restrict__ offs, float* __restrict__ agg) {
    int n = blockIdx.x; int h = threadIdx.x;
    int lo = offs[n], hi = offs[n + 1];
    float a = 0.f;
    for (int j = lo; j < hi; j++) {
        int e = elist[j];
        a += Ht[e * HID + h];
    }
    agg[n * HID + h] = a;
}

__global__ void k_edge_update(const float* __restrict__ H0, const float* __restrict__ Htin,
                              const float* __restrict__ agg,
                              const int* __restrict__ src, const int* __restrict__ rev,
                              const float* __restrict__ Wh, const float* __restrict__ bh,
                              float* __restrict__ Htout) {
    __shared__ float M[EB][HID];
    int e0 = blockIdx.x * EB;
    int h = threadIdx.x;
    for (int j = 0; j < EB; j++) {
        int e = e0 + j; int s = src[e]; int r = rev[e];
        M[j][h] = agg[s * HID + h] - Htin[r * HID + h];
    }
    __syncthreads();
    float acc[EB];
#pragma unroll
    for (int j = 0; j < EB; j++) acc[j] = 0.f;
    for (int k = 0; k < HID; k++) {
        float w = Wh[k * HID + h];
#pragma unroll
        for (int j = 0; j < EB; j++) acc[j] = fmaf(M[j][k], w, acc[j]);
    }
    float b = bh[h];
    for (int j = 0; j < EB; j++) {
        int e = e0 + j;
        Htout[e * HID + h] = fmaxf(H0[e * HID + h] + acc[j] + b, 0.f);
    }
}

__global__ void k_node_embed(const float* __restrict__ x, const float* __restrict__ agg,
                             const float* __restrict__ Wnt, const float* __restrict__ bnt,
                             const float* __restrict__ Wo, const float* __restrict__ bo,
                             float* __restrict__ Emb) {
    __shared__ float xs[ND + 1];
    __shared__ float Ms[HID];
    __shared__ float red[HID];
    int n = blockIdx.x; int h = threadIdx.x;
    for (int k = h; k < ND; k += HID) xs[k] = x[n * ND + k];
    float a = agg[n * HID + h];
    red[h] = a;
    __syncthreads();
    for (int st = 64; st > 0; st >>= 1) { if (h < st) red[h] += red[h + st]; __syncthreads(); }
    float s = red[0];
    __syncthreads();
    float Mh;
    if (s == 0.0f) {
        float t0 = 0.f, t1 = 0.f;
        int k = 0;
        for (; k + 1 < ND; k += 2) {
            t0 = fmaf(xs[k], Wnt[k * HID + h], t0);
            t1 = fmaf(xs[k + 1], Wnt[(k + 1) * HID + h], t1);
        }
        for (; k < ND; k++) t0 = fmaf(xs[k], Wnt[k * HID + h], t0);
        Mh = (t0 + t1) + bnt[h];
    } else {
        Mh = a;
    }
    Ms[h] = Mh;
    __syncthreads();
    float a0 = 0.f, a1 = 0.f;
    int k = 0;
    for (; k + 1 < ND; k += 2) {
        a0 = fmaf(xs[k], Wo[k * HID + h], a0);
        a1 = fmaf(xs[k + 1], Wo[(k + 1) * HID + h], a1);
    }
    for (; k < ND; k++) a0 = fmaf(xs[k], Wo[k * HID + h], a0);
    for (int q = 0; q < HID; q += 2) {
        a0 = fmaf(Ms[q], Wo[(ND + q) * HID + h], a0);
        a1 = fmaf(Ms[q + 1], Wo[(ND + q + 1) * HID + h], a1);
    }
    Emb[n * HID + h] = fmaxf((a0 + a1) + bo[h], 0.f);
}

// ---------------- valid-node compaction (1 block, 1024 threads) ----------------

__global__ void k_build_valid2(const float* __restrict__ pka, int* validIdx, int* NvP, int* vpos) {
    __shared__ int s[NN];
    int t = threadIdx.x;
    float v = pka[t];
    int f = (v == v) ? 1 : 0;   // !isnan
    s[t] = f;
    __syncthreads();
    for (int st = 1; st < NN; st <<= 1) {
        int u = (t >= st) ? s[t - st] : 0;
        __syncthreads();
        s[t] += u;
        __syncthreads();
    }
    int incl = s[t];
    int pos = incl - f;
    int ok = (f && pos < NVMAX) ? 1 : 0;
    vpos[t] = ok ? pos : -1;
    if (ok) validIdx[pos] = t;
    if (t == NN - 1) *NvP = (incl > NVMAX) ? NVMAX : incl;
}

// ---------------- speculative gate chains (Wg in registers, 512 threads) ----------------

__global__ void __launch_bounds__(512)
k_chains3(const float* __restrict__ Emb, const int* __restrict__ validIdx,
          const int* __restrict__ NvP,
          const float* __restrict__ Wg, const float* __restrict__ bg,
          float* __restrict__ specSt) {
    int v = blockIdx.x;
    int Nv = *NvP;
    if (v >= Nv) return;
    __shared__ float rS[HID];
    __shared__ float pS[512];
    int tid = threadIdx.x;
    int col = tid & (HID - 1);
    int slot = tid >> 7;            // 0..3, K-slice [slot*32, slot*32+32)
    // Wg K-slice for this thread's column, in registers (coalesced load)
    float wreg[32];
#pragma unroll
    for (int q = 0; q < 32; q++)
        wreg[q] = Wg[(slot * 32 + q) * HID + col];
    float bgc = bg[col];
    int i = validIdx[v];
    if (tid < HID) rS[tid] = Emb[i * HID + tid];
    __syncthreads();
    if (slot == 0) specSt[(size_t)(v * NVMAX + 0) * HID + col] = rS[col];
    int kmax = (v < NVMAX - 1) ? v : (NVMAX - 1);
    for (int k = 1; k <= kmax; k++) {
        // partial dot over this thread's 32-K slice (state via b128 broadcast reads)
        const float4* r4 = (const float4*)&rS[slot * 32];
        float px = 0.f, py = 0.f, pz = 0.f, pw = 0.f;
#pragma unroll
        for (int q8 = 0; q8 < 8; q8++) {
            float4 rr = r4[q8];
            px = fmaf(rr.x, wreg[4 * q8 + 0], px);
            py = fmaf(rr.y, wreg[4 * q8 + 1], py);
            pz = fmaf(rr.z, wreg[4 * q8 + 2], pz);
            pw = fmaf(rr.w, wreg[4 * q8 + 3], pw);
        }
        pS[tid] = (px + py) + (pz + pw);
        __syncthreads();
        if (slot == 0) {
            float s = ((pS[col] + pS[col + 128]) + (pS[col + 256] + pS[col + 384])) + bgc;
            float g = 1.0f - sigm(s);
            float nr = rS[col] * g;
            rS[col] = nr;
            specSt[(size_t)(v * NVMAX + k) * HID + col] = nr;
        }
        __syncthreads();
    }
}

// ---------------- active-pair compaction ----------------

__global__ void k_pairs(const int* __restrict__ NvP, const int* __restrict__ mask,
                        const int* __restrict__ validIdx, int* pairCnt, int* pairList) {
    int t = blockIdx.x * blockDim.x + threadIdx.x;  // over NVMAX*NVMAX
    int v = t >> 7, k = t & (NVMAX - 1);
    int Nv = *NvP;
    if (v < Nv && k <= v && mask[validIdx[v]] == 0) {
        int p = atomicAdd(pairCnt, 1);
        pairList[p] = t;
    }
}

// ---------------- batched classifier table (JT pairs per block) ----------------

__global__ void k_table2(const float* __restrict__ specSt, const int* __restrict__ pairList,
                         const int* __restrict__ pairCnt,
                         const float* __restrict__ Wc1, const float* __restrict__ bc1,
                         const float* __restrict__ Wc2, const float* __restrict__ bc2,
                         const float* __restrict__ Wc3, const float* __restrict__ bc3,
                         int* __restrict__ labTab) {
    int cnt = *pairCnt;
    int base = blockIdx.x * JT;
    if (base >= cnt) return;
    int nj = cnt - base; if (nj > JT) nj = JT;
    __shared__ float rS[JT][HID];
    __shared__ float h1S[JT][256];
    __shared__ float h2S[JT][64];
    __shared__ int plS[JT];
    int tid = threadIdx.x;  // 256
    if (tid < JT) plS[tid] = (tid < nj) ? pairList[base + tid] : 0;
    __syncthreads();
    for (int idx = tid; idx < JT * HID; idx += 256) {
        int j = idx >> 7, k = idx & (HID - 1);
        rS[j][k] = (j < nj) ? specSt[(size_t)plS[j] * HID + k] : 0.f;
    }
    __syncthreads();
    // layer 1: 128 -> 256
    float a[JT];
#pragma unroll
    for (int j = 0; j < JT; j++) a[j] = 0.f;
    for (int k = 0; k < HID; k++) {
        float w = Wc1[k * 256 + tid];
#pragma unroll
        for (int j = 0; j < JT; j++) a[j] = fmaf(rS[j][k], w, a[j]);
    }
    float b1 = bc1[tid];
#pragma unroll
    for (int j = 0; j < JT; j++) h1S[j][tid] = fmaxf(a[j] + b1, 0.f);
    __syncthreads();
    // layer 2: 256 -> 64; 4 groups x 64 cols, each group handles 2 pairs
    {
        int col = tid & 63, g2 = (tid >> 6) * 2;
        float b0 = 0.f, bb1 = 0.f;
        for (int k = 0; k < 256; k++) {
            float w = Wc2[k * 64 + col];
            b0 = fmaf(h1S[g2][k], w, b0);
            bb1 = fmaf(h1S[g2 + 1][k], w, bb1);
        }
        float b2 = bc2[col];
        h2S[g2][col] = fmaxf(b0 + b2, 0.f);
        h2S[g2 + 1][col] = fmaxf(bb1 + b2, 0.f);
    }
    __syncthreads();
    // layer 3 + decision
    if (tid < nj) {
        float l0 = bc3[0], l1 = bc3[1];
        for (int k = 0; k < 64; k++) {
            float h = h2S[tid][k];
            l0 = fmaf(h, Wc3[2 * k + 0], l0);
            l1 = fmaf(h, Wc3[2 * k + 1], l1);
        }
        labTab[plS[tid]] = (l1 > l0) ? 1 : 0;
    }
}

// ---------------- fast resolve (1 block, 1024 threads, LDS walk + scan) ----------------

__global__ void k_resolve2(const int* __restrict__ validIdx, const int* __restrict__ NvP,
                           const int* __restrict__ mask, const int* __restrict__ labTab,
                           int* fireFlag, int* kPref) {
    __shared__ int vIdxS[NVMAX];
    __shared__ int maskS[NVMAX];
    __shared__ int labS[NVMAX * NVMAX];
    __shared__ int fireS[NN];
    __shared__ int scanS[NN];
    int t = threadIdx.x;
    int Nv = *NvP;
    if (t < NVMAX) {
        int vi = (t < Nv) ? validIdx[t] : 0;
        vIdxS[t] = vi;
        maskS[t] = (t < Nv) ? mask[vi] : 0;
    }
    fireS[t] = 0;
    for (int idx = t; idx < Nv * NVMAX; idx += NN) labS[idx] = labTab[idx];
    __syncthreads();
    if (t == 0) {
        int k = 0;
        for (int v = 0; v < Nv; v++) {
            int fire = (maskS[v] > 0) ? 1 : labS[v * NVMAX + k];
            fireS[vIdxS[v]] = fire;
            k += fire;
        }
    }
    __syncthreads();
    int f0 = fireS[t];
    scanS[t] = f0;
    __syncthreads();
    for (int st = 1; st < NN; st <<= 1) {
        int u = (t >= st) ? scanS[t - st] : 0;
        __syncthreads();
        scanS[t] += u;
        __syncthreads();
    }
    kPref[t] = scanS[t] - f0;
    fireFlag[t] = f0;
}

// ---------------- fused final pass: JF nodes per block ----------------

__global__ void __launch_bounds__(256)
k_final2(const float* __restrict__ Emb, const int* __restrict__ kPref,
         const int* __restrict__ fireFlag, const int* __restrict__ mask,
         const float* __restrict__ pka, const int* __restrict__ vpos,
         const int* __restrict__ labTab,
         const float* __restrict__ Wg, const float* __restrict__ bg,
         const float* __restrict__ Wc1, const float* __restrict__ bc1,
         const float* __restrict__ Wc2, const float* __restrict__ bc2,
         const float* __restrict__ Wc3, const float* __restrict__ bc3,
         const float* __restrict__ Wr1, const float* __restrict__ br1,
         const float* __restrict__ Wr2, const float* __restrict__ br2,
         const float* __restrict__ Wr3, const float* __restrict__ br3,
         float* __restrict__ outLabels, float* __restrict__ outPreds,
         float* __restrict__ ceArr, float* __restrict__ regArr,
         float* __restrict__ corArr) {
    __shared__ float WgS[HID * HID];       // 64 KB
    __shared__ float rS[JF][HID];
    __shared__ float h1S[JF][256];
    __shared__ float h2S[JF][64];
    __shared__ float lgS[JF][2];
    __shared__ float prS[JF];
    __shared__ int kcS[JF];
    int tid = threadIdx.x;  // 256
    int i0 = blockIdx.x * JF;

    const float4* Wg4 = (const float4*)Wg;
    float4* Ws4 = (float4*)WgS;
    for (int idx = tid; idx < HID * HID / 4; idx += 256) Ws4[idx] = Wg4[idx];
    if (tid < HID) {
#pragma unroll
        for (int j = 0; j < JF; j++) rS[j][tid] = Emb[(i0 + j) * HID + tid];
    }
    if (tid < JF) kcS[tid] = kPref[i0 + tid];
    __syncthreads();
    int kc[JF]; int maxkc = 0;
#pragma unroll
    for (int j = 0; j < JF; j++) { kc[j] = kcS[j]; if (kc[j] > maxkc) maxkc = kc[j]; }

    // ---- gate rounds: each thread handles (col, 2 nodes of its slot) ----
    int col = tid & (HID - 1);
    int slot = tid >> 7;           // 0 -> nodes {0,1}, 1 -> nodes {2,3}
    int j0 = slot * 2, j1 = slot * 2 + 1;
    float bgc = bg[col];
    for (int t = 0; t < maxkc; t++) {
        float a00 = 0.f, a01 = 0.f, a02 = 0.f, a03 = 0.f;
        float a10 = 0.f, a11 = 0.f, a12 = 0.f, a13 = 0.f;
        for (int q = 0; q < HID; q += 4) {
            float w0 = WgS[(q + 0) * HID + col];
            float w1 = WgS[(q + 1) * HID + col];
            float w2 = WgS[(q + 2) * HID + col];
            float w3 = WgS[(q + 3) * HID + col];
            a00 = fmaf(rS[j0][q + 0], w0, a00);
            a01 = fmaf(rS[j0][q + 1], w1, a01);
            a02 = fmaf(rS[j0][q + 2], w2, a02);
            a03 = fmaf(rS[j0][q + 3], w3, a03);
            a10 = fmaf(rS[j1][q + 0], w0, a10);
            a11 = fmaf(rS[j1][q + 1], w1, a11);
            a12 = fmaf(rS[j1][q + 2], w2, a12);
            a13 = fmaf(rS[j1][q + 3], w3, a13);
        }
        float g0 = 1.0f - sigm(((a00 + a01) + (a02 + a03)) + bgc);
        float g1 = 1.0f - sigm(((a10 + a11) + (a12 + a13)) + bgc);
        __syncthreads();
        if (t < kc[j0]) rS[j0][col] *= g0;
        if (t < kc[j1]) rS[j1][col] *= g1;
        __syncthreads();
    }

    // ---- classifier: layer1 128->256 ----
    {
        float a[JF];
#pragma unroll
        for (int j = 0; j < JF; j++) a[j] = 0.f;
        for (int k = 0; k < HID; k++) {
            float w = Wc1[k * 256 + tid];
#pragma unroll
            for (int j = 0; j < JF; j++) a[j] = fmaf(rS[j][k], w, a[j]);
        }
        float b = bc1[tid];
#pragma unroll
        for (int j = 0; j < JF; j++) h1S[j][tid] = fmaxf(a[j] + b, 0.f);
    }
    __syncthreads();
    // layer2 256->64: 4 groups of 64 cols, group handles node j=group
    {
        int c2 = tid & 63, j = tid >> 6;
        float acc = 0.f;
        for (int k = 0; k < 256; k++) acc = fmaf(h1S[j][k], Wc2[k * 64 + c2], acc);
        h2S[j][c2] = fmaxf(acc + bc2[c2], 0.f);
    }
    __syncthreads();
    // layer3 64->2
    if (tid < 2 * JF) {
        int j = tid >> 1, c = tid & 1;
        float l = bc3[c];
        for (int k = 0; k < 64; k++) l = fmaf(h2S[j][k], Wc3[2 * k + c], l);
        lgS[j][c] = l;
    }
    __syncthreads();

    // ---- regressor: layer1 ----
    {
        float a[JF];
#pragma unroll
        for (int j = 0; j < JF; j++) a[j] = 0.f;
        for (int k = 0; k < HID; k++) {
            float w = Wr1[k * 256 + tid];
#pragma unroll
            for (int j = 0; j < JF; j++) a[j] = fmaf(rS[j][k], w, a[j]);
        }
        float b = br1[tid];
#pragma unroll
        for (int j = 0; j < JF; j++) h1S[j][tid] = fmaxf(a[j] + b, 0.f);
    }
    __syncthreads();
    {
        int c2 = tid & 63, j = tid >> 6;
        float acc = 0.f;
        for (int k = 0; k < 256; k++) acc = fmaf(h1S[j][k], Wr2[k * 64 + c2], acc);
        h2S[j][c2] = fmaxf(acc + br2[c2], 0.f);
    }
    __syncthreads();
    if (tid < JF) {
        float pr = br3[0];
        for (int k = 0; k < 64; k++) pr = fmaf(h2S[tid][k], Wr3[k], pr);
        prS[tid] = pr;
    }
    __syncthreads();

    // ---- per-node outputs ----
    if (tid < JF) {
        int j = tid, i = i0 + j;
        float l0 = lgS[j][0], l1 = lgS[j][1];
        int compLab = (l1 > l0) ? 1 : 0;
        int vp = vpos[i];
        int label = (vp >= 0 && mask[i] == 0) ? labTab[vp * NVMAX + kc[j]] : compLab;
        int target = (mask[i] > 0) ? 1 : 0;
        float mx = fmaxf(l0, l1);
        float lse = mx + logf(expf(l0 - mx) + expf(l1 - mx));
        float ce = lse - ((target == 1) ? l1 : l0);
        int reg_cond = (label == 1) || (mask[i] > 0);
        float p = sigm(prS[j]);
        p = fminf(fmaxf(p, 0.f), 14.f);
        outLabels[i] = (float)label;
        outPreds[i] = reg_cond ? p : 0.f;
        ceArr[i] = ce;
        corArr[i] = (label == target) ? 1.f : 0.f;
        if (fireFlag[i]) {
            float d = p - pka[i];
            regArr[i] = d * d;
        } else {
            regArr[i] = 0.f;
        }
    }
}

__global__ void k_loss(const float* __restrict__ ceArr, const float* __restrict__ regArr,
                       const float* __restrict__ corArr, float* __restrict__ out) {
    __shared__ float s[NN];
    int t = threadIdx.x;
    s[t] = ceArr[t]; __syncthreads();
    for (int st = 512; st > 0; st >>= 1) { if (t < st) s[t] += s[t + st]; __syncthreads(); }
    float cls = s[0]; __syncthreads();
    s[t] = regArr[t]; __syncthreads();
    for (int st = 512; st > 0; st >>= 1) { if (t < st) s[t] += s[t + st]; __syncthreads(); }
    float reg = s[0]; __syncthreads();
    s[t] = corArr[t]; __syncthreads();
    for (int st = 512; st > 0; st >>= 1) { if (t < st) s[t] += s[t + st]; __syncthreads(); }
    float cor = s[0];
    if (t == 0) {
        out[0] = cls + reg;
        out[1] = cls;
        out[2] = reg;
        out[3] = cor / (float)NN;
    }
}

// ---------------- launch ----------------

extern "C" void kernel_launch(void* const* d_in, const int* in_sizes, int n_in,
                              void* d_out, int out_size, void* d_ws, size_t ws_size,
                              hipStream_t stream) {
    const float* x    = (const float*)d_in[0];
    const float* ea   = (const float*)d_in[1];
    const float* pka  = (const float*)d_in[2];
    const int*   mask = (const int*)d_in[3];
    const int*   eidx = (const int*)d_in[4];
    const int*   rev  = (const int*)d_in[5];
    const float* Wi  = (const float*)d_in[6];  const float* bi  = (const float*)d_in[7];
    const float* Wh  = (const float*)d_in[8];  const float* bh  = (const float*)d_in[9];
    const float* Wo  = (const float*)d_in[10]; const float* bo  = (const float*)d_in[11];
    const float* Wnt = (const float*)d_in[12]; const float* bnt = (const float*)d_in[13];
    const float* Wc1 = (const float*)d_in[14]; const float* bc1 = (const float*)d_in[15];
    const float* Wc2 = (const float*)d_in[16]; const float* bc2 = (const float*)d_in[17];
    const float* Wc3 = (const float*)d_in[18]; const float* bc3 = (const float*)d_in[19];
    const float* Wr1 = (const float*)d_in[20]; const float* br1 = (const float*)d_in[21];
    const float* Wr2 = (const float*)d_in[22]; const float* br2 = (const float*)d_in[23];
    const float* Wr3 = (const float*)d_in[24]; const float* br3 = (const float*)d_in[25];
    const float* Wg  = (const float*)d_in[26]; const float* bg  = (const float*)d_in[27];

    const int* src = eidx;
    const int* dst = eidx + NE;

    char* w = (char*)d_ws;
    auto alloc = [&](size_t bytes) -> void* {
        void* p = (void*)w;
        w += ((bytes + 255) / 256) * 256;
        return p;
    };
    float* H0   = (float*)alloc((size_t)NE * HID * 4);
    float* HtA  = (float*)alloc((size_t)NE * HID * 4);
    float* HtB  = (float*)alloc((size_t)NE * HID * 4);
    float* agg  = (float*)alloc((size_t)NN * HID * 4);
    float* Emb  = (float*)alloc((size_t)NN * HID * 4);
    int* deg     = (int*)alloc(NN * 4);
    int* offs    = (int*)alloc((NN + 1) * 4);
    int* fillpos = (int*)alloc(NN * 4);
    int* elist   = (int*)alloc(NE * 4);
    int* validIdx= (int*)alloc(NVMAX * 4);
    int* NvP     = (int*)alloc(16);
    int* vpos    = (int*)alloc(NN * 4);
    int* fireFlag= (int*)alloc(NN * 4);
    int* kPref   = (int*)alloc(NN * 4);
    float* specSt= (float*)alloc((size_t)NVMAX * NVMAX * HID * 4);
    int* labTab  = (int*)alloc(NVMAX * NVMAX * 4);
    int* pairCnt = (int*)alloc(16);
    int* pairList= (int*)alloc(MAXPAIRS * 4);
    float* ceArr = (float*)alloc(NN * 4);
    float* regArr= (float*)alloc(NN * 4);
    float* corArr= (float*)alloc(NN * 4);

    float* outF = (float*)d_out;  // [labels 1024][preds 1024][loss 4]

    hipMemsetAsync(deg, 0, NN * 4, stream);
    hipMemsetAsync(pairCnt, 0, 4, stream);

    k_count<<<NE / 256, 256, 0, stream>>>(dst, deg);
    k_scan_offsets<<<1, NN, 0, stream>>>(deg, offs, fillpos);
    k_fill<<<NE / 256, 256, 0, stream>>>(dst, fillpos, elist);
    k_sort<<<(NN + 255) / 256, 256, 0, stream>>>(elist, offs);

    k_edge_init<<<NE / EB, HID, 0, stream>>>(x, ea, src, Wi, bi, H0, HtA);
    k_segsum<<<NN, HID, 0, stream>>>(HtA, elist, offs, agg);
    k_edge_update<<<NE / EB, HID, 0, stream>>>(H0, HtA, agg, src, rev, Wh, bh, HtB);
    k_segsum<<<NN, HID, 0, stream>>>(HtB, elist, offs, agg);
    k_edge_update<<<NE / EB, HID, 0, stream>>>(H0, HtB, agg, src, rev, Wh, bh, HtA);
    k_segsum<<<NN, HID, 0, stream>>>(HtA, elist, offs, agg);
    k_node_embed<<<NN, HID, 0, stream>>>(x, agg, Wnt, bnt, Wo, bo, Emb);

    k_build_valid2<<<1, NN, 0, stream>>>(pka, validIdx, NvP, vpos);
    k_chains3<<<NVMAX, 512, 0, stream>>>(Emb, validIdx, NvP, Wg, bg, specSt);
    k_pairs<<<(NVMAX * NVMAX) / 256, 256, 0, stream>>>(NvP, mask, validIdx, pairCnt, pairList);
    k_table2<<<(MAXPAIRS + JT - 1) / JT, 256, 0, stream>>>(specSt, pairList, pairCnt,
                                                           Wc1, bc1, Wc2, bc2, Wc3, bc3, labTab);
    k_resolve2<<<1, NN, 0, stream>>>(validIdx, NvP, mask, labTab, fireFlag, kPref);

    k_final2<<<NN / JF, 256, 0, stream>>>(Emb, kPref, fireFlag, mask, pka, vpos, labTab,
                                          Wg, bg, Wc1, bc1, Wc2, bc2, Wc3, bc3,
                                          Wr1, br1, Wr2, br2, Wr3, br3,
                                          outF, outF + NN, ceArr, regArr, corArr);
    k_loss<<<1, NN, 0, stream>>>(ceArr, regArr, corArr, outF + 2 * NN);
}

// Round 4
// 257.422 us; speedup vs baseline: 2.7589x; 1.1506x over previous
//
#include <hip/hip_runtime.h>

#define NN   1024
#define NE   16384
#define HID  128
#define ND   133
#define BD   14
#define KIN  147   // ND + BD
#define NVMAX 128
#define EB   8     // edges per block in edge kernels
#define JF   4     // nodes per block in final pass
#define JT   8     // pairs per block in table pass
#define SBCAP 63   // max staged segment length in k_sort2
#define MAXPAIRS (NVMAX * (NVMAX + 1) / 2)

// ---------------- shared device math ----------------

__device__ __forceinline__ float sigm(float x) { return 1.0f / (1.0f + expf(-x)); }

// ---------------- CSR build (deterministic: int atomics + per-node sort) ----------------

__global__ void k_count(const int* __restrict__ dst, int* deg) {
    int e = blockIdx.x * blockDim.x + threadIdx.x;
    if (e < NE) atomicAdd(&deg[dst[e]], 1);
}

// merged: offsets scan + valid-node compaction + active-pair list (1 block, 1024 thr)
__global__ void __launch_bounds__(1024)
k_prep(const int* __restrict__ deg, int* offs, int* fillpos,
       const float* __restrict__ pka, int* validIdx, int* NvP, int* vpos,
       const int* __restrict__ mask, int* pairCnt, int* pairList) {
    __shared__ int s[NN];
    __shared__ int s2[NN];
    __shared__ int vIdxS[NVMAX];
    __shared__ int maskS[NVMAX];
    __shared__ int nvS;
    __shared__ int pcS;
    int t = threadIdx.x;
    int d0 = deg[t];
    s[t] = d0;
    float v = pka[t];
    int f = (v == v) ? 1 : 0;   // !isnan
    s2[t] = f;
    __syncthreads();
    for (int st = 1; st < NN; st <<= 1) {
        int a = (t >= st) ? s[t - st] : 0;
        int b = (t >= st) ? s2[t - st] : 0;
        __syncthreads();
        s[t] += a; s2[t] += b;
        __syncthreads();
    }
    offs[t] = s[t] - d0;
    fillpos[t] = s[t] - d0;
    if (t == NN - 1) offs[NN] = s[t];
    int pos = s2[t] - f;
    int ok = (f && pos < NVMAX) ? 1 : 0;
    vpos[t] = ok ? pos : -1;
    if (ok) { validIdx[pos] = t; vIdxS[pos] = t; }
    if (t == NN - 1) { int nv = (s2[t] > NVMAX) ? NVMAX : s2[t]; *NvP = nv; nvS = nv; }
    if (t == 0) pcS = 0;
    __syncthreads();
    int Nv = nvS;
    if (t < NVMAX) maskS[t] = (t < Nv) ? mask[vIdxS[t]] : 1;
    __syncthreads();
    for (int idx = t; idx < NVMAX * NVMAX; idx += NN) {
        int vv = idx >> 7, k = idx & (NVMAX - 1);
        if (vv < Nv && k <= vv && maskS[vv] == 0) {
            int p = atomicAdd(&pcS, 1);
            pairList[p] = idx;
        }
    }
    __syncthreads();
    if (t == 0) *pairCnt = pcS;
}

__global__ void k_fill(const int* __restrict__ dst, int* fillpos, int* elist) {
    int e = blockIdx.x * blockDim.x + threadIdx.x;
    if (e < NE) { int p = atomicAdd(&fillpos[dst[e]], 1); elist[p] = e; }
}

// LDS-staged per-node insertion sort (transposed layout: bank = t%32, conflict-light)
__global__ void __launch_bounds__(256)
k_sort2(int* elist, const int* __restrict__ offs) {
    __shared__ int buf[SBCAP][256];
    int t = threadIdx.x;
    int n = blockIdx.x * 256 + t;
    int lo = offs[n], hi = offs[n + 1];
    int d = hi - lo;
    if (d <= SBCAP) {
        for (int j = 0; j < d; j++) buf[j][t] = elist[lo + j];
        for (int a = 1; a < d; a++) {
            int vv = buf[a][t]; int b = a - 1;
            while (b >= 0 && buf[b][t] > vv) { buf[b + 1][t] = buf[b][t]; b--; }
            buf[b + 1][t] = vv;
        }
        for (int j = 0; j < d; j++) elist[lo + j] = buf[j][t];
    } else {
        for (int a = lo + 1; a < hi; a++) {
            int vv = elist[a]; int b = a - 1;
            while (b >= lo && elist[b] > vv) { elist[b + 1] = elist[b]; b--; }
            elist[b + 1] = vv;
        }
    }
}

// ---------------- message passing ----------------

__global__ void k_edge_init(const float* __restrict__ x, const float* __restrict__ ea,
                            const int* __restrict__ src,
                            const float* __restrict__ Wi, const float* __restrict__ bi,
                            float* __restrict__ H0, float* __restrict__ Ht) {
    __shared__ float in[EB][KIN + 1];
    int e0 = blockIdx.x * EB;
    int h = threadIdx.x;
    for (int j = 0; j < EB; j++) {
        int e = e0 + j; int s = src[e];
        for (int k = h; k < KIN; k += HID)
            in[j][k] = (k < ND) ? x[s * ND + k] : ea[e * BD + (k - ND)];
    }
    __syncthreads();
    float acc[EB];
#pragma unroll
    for (int j = 0; j < EB; j++) acc[j] = 0.f;
    for (int k = 0; k < KIN; k++) {
        float w = Wi[k * HID + h];
#pragma unroll
        for (int j = 0; j < EB; j++) acc[j] = fmaf(in[j][k], w, acc[j]);
    }
    float b = bi[h];
    for (int j = 0; j < EB; j++) {
        float v = acc[j] + b;
        H0[(e0 + j) * HID + h] = v;
        Ht[(e0 + j) * HID + h] = fmaxf(v, 0.f);
    }
}

__global__ void k_segsum(const float* __restrict__ Ht, const int* __restrict__ elist,
                         const int* __restrict__ offs, float* __restrict__ agg) {
    int n = blockIdx.x; int h = threadIdx.x;
    int lo = offs[n], hi = offs[n + 1];
    float a = 0.f;
    for (int j = lo; j < hi; j++) {
        int e = elist[j];
        a += Ht[e * HID + h];
    }
    agg[n * HID + h] = a;
}

__global__ void k_edge_update(const float* __restrict__ H0, const float* __restrict__ Htin,
                              const float* __restrict__ agg,
                              const int* __restrict__ src, const int* __restrict__ rev,
                              const float* __restrict__ Wh, const float* __restrict__ bh,
                              float* __restrict__ Htout) {
    __shared__ float M[EB][HID];
    int e0 = blockIdx.x * EB;
    int h = threadIdx.x;
    for (int j = 0; j < EB; j++) {
        int e = e0 + j; int s = src[e]; int r = rev[e];
        M[j][h] = agg[s * HID + h] - Htin[r * HID + h];
    }
    __syncthreads();
    float acc[EB];
#pragma unroll
    for (int j = 0; j < EB; j++) acc[j] = 0.f;
    for (int k = 0; k < HID; k++) {
        float w = Wh[k * HID + h];
#pragma unroll
        for (int j = 0; j < EB; j++) acc[j] = fmaf(M[j][k], w, acc[j]);
    }
    float b = bh[h];
    for (int j = 0; j < EB; j++) {
        int e = e0 + j;
        Htout[e * HID + h] = fmaxf(H0[e * HID + h] + acc[j] + b, 0.f);
    }
}

__global__ void k_node_embed(const float* __restrict__ x, const float* __restrict__ agg,
                             const float* __restrict__ Wnt, const float* __restrict__ bnt,
                             const float* __restrict__ Wo, const float* __restrict__ bo,
                             float* __restrict__ Emb) {
    __shared__ float xs[ND + 1];
    __shared__ float Ms[HID];
    __shared__ float red[HID];
    int n = blockIdx.x; int h = threadIdx.x;
    for (int k = h; k < ND; k += HID) xs[k] = x[n * ND + k];
    float a = agg[n * HID + h];
    red[h] = a;
    __syncthreads();
    for (int st = 64; st > 0; st >>= 1) { if (h < st) red[h] += red[h + st]; __syncthreads(); }
    float s = red[0];
    __syncthreads();
    float Mh;
    if (s == 0.0f) {
        float t0 = 0.f, t1 = 0.f;
        int k = 0;
        for (; k + 1 < ND; k += 2) {
            t0 = fmaf(xs[k], Wnt[k * HID + h], t0);
            t1 = fmaf(xs[k + 1], Wnt[(k + 1) * HID + h], t1);
        }
        for (; k < ND; k++) t0 = fmaf(xs[k], Wnt[k * HID + h], t0);
        Mh = (t0 + t1) + bnt[h];
    } else {
        Mh = a;
    }
    Ms[h] = Mh;
    __syncthreads();
    float a0 = 0.f, a1 = 0.f;
    int k = 0;
    for (; k + 1 < ND; k += 2) {
        a0 = fmaf(xs[k], Wo[k * HID + h], a0);
        a1 = fmaf(xs[k + 1], Wo[(k + 1) * HID + h], a1);
    }
    for (; k < ND; k++) a0 = fmaf(xs[k], Wo[k * HID + h], a0);
    for (int q = 0; q < HID; q += 2) {
        a0 = fmaf(Ms[q], Wo[(ND + q) * HID + h], a0);
        a1 = fmaf(Ms[q + 1], Wo[(ND + q + 1) * HID + h], a1);
    }
    Emb[n * HID + h] = fmaxf((a0 + a1) + bo[h], 0.f);
}

// ---------------- speculative gate chains (Wg in registers, 512 threads) ----------------

__global__ void __launch_bounds__(512)
k_chains3(const float* __restrict__ Emb, const int* __restrict__ validIdx,
          const int* __restrict__ NvP,
          const float* __restrict__ Wg, const float* __restrict__ bg,
          float* __restrict__ specSt) {
    int v = blockIdx.x;
    int Nv = *NvP;
    if (v >= Nv) return;
    __shared__ float rS[HID];
    __shared__ float pS[512];
    int tid = threadIdx.x;
    int col = tid & (HID - 1);
    int slot = tid >> 7;            // 0..3, K-slice [slot*32, slot*32+32)
    float wreg[32];
#pragma unroll
    for (int q = 0; q < 32; q++)
        wreg[q] = Wg[(slot * 32 + q) * HID + col];
    float bgc = bg[col];
    int i = validIdx[v];
    if (tid < HID) rS[tid] = Emb[i * HID + tid];
    __syncthreads();
    if (slot == 0) specSt[(size_t)(v * NVMAX + 0) * HID + col] = rS[col];
    int kmax = (v < NVMAX - 1) ? v : (NVMAX - 1);
    for (int k = 1; k <= kmax; k++) {
        const float4* r4 = (const float4*)&rS[slot * 32];
        float px = 0.f, py = 0.f, pz = 0.f, pw = 0.f;
#pragma unroll
        for (int q8 = 0; q8 < 8; q8++) {
            float4 rr = r4[q8];
            px = fmaf(rr.x, wreg[4 * q8 + 0], px);
            py = fmaf(rr.y, wreg[4 * q8 + 1], py);
            pz = fmaf(rr.z, wreg[4 * q8 + 2], pz);
            pw = fmaf(rr.w, wreg[4 * q8 + 3], pw);
        }
        pS[tid] = (px + py) + (pz + pw);
        __syncthreads();
        if (slot == 0) {
            float s = ((pS[col] + pS[col + 128]) + (pS[col + 256] + pS[col + 384])) + bgc;
            float g = 1.0f - sigm(s);
            float nr = rS[col] * g;
            rS[col] = nr;
            specSt[(size_t)(v * NVMAX + k) * HID + col] = nr;
        }
        __syncthreads();
    }
}

// ---------------- batched classifier table (JT pairs per block) ----------------

__global__ void k_table2(const float* __restrict__ specSt, const int* __restrict__ pairList,
                         const int* __restrict__ pairCnt,
                         const float* __restrict__ Wc1, const float* __restrict__ bc1,
                         const float* __restrict__ Wc2, const float* __restrict__ bc2,
                         const float* __restrict__ Wc3, const float* __restrict__ bc3,
                         int* __restrict__ labTab) {
    int cnt = *pairCnt;
    int base = blockIdx.x * JT;
    if (base >= cnt) return;
    int nj = cnt - base; if (nj > JT) nj = JT;
    __shared__ float rS[JT][HID];
    __shared__ float h1S[JT][256];
    __shared__ float h2S[JT][64];
    __shared__ int plS[JT];
    int tid = threadIdx.x;  // 256
    if (tid < JT) plS[tid] = (tid < nj) ? pairList[base + tid] : 0;
    __syncthreads();
    for (int idx = tid; idx < JT * HID; idx += 256) {
        int j = idx >> 7, k = idx & (HID - 1);
        rS[j][k] = (j < nj) ? specSt[(size_t)plS[j] * HID + k] : 0.f;
    }
    __syncthreads();
    float a[JT];
#pragma unroll
    for (int j = 0; j < JT; j++) a[j] = 0.f;
    for (int k = 0; k < HID; k++) {
        float w = Wc1[k * 256 + tid];
#pragma unroll
        for (int j = 0; j < JT; j++) a[j] = fmaf(rS[j][k], w, a[j]);
    }
    float b1 = bc1[tid];
#pragma unroll
    for (int j = 0; j < JT; j++) h1S[j][tid] = fmaxf(a[j] + b1, 0.f);
    __syncthreads();
    {
        int col = tid & 63, g2 = (tid >> 6) * 2;
        float b0 = 0.f, bb1 = 0.f;
        for (int k = 0; k < 256; k++) {
            float w = Wc2[k * 64 + col];
            b0 = fmaf(h1S[g2][k], w, b0);
            bb1 = fmaf(h1S[g2 + 1][k], w, bb1);
        }
        float b2 = bc2[col];
        h2S[g2][col] = fmaxf(b0 + b2, 0.f);
        h2S[g2 + 1][col] = fmaxf(bb1 + b2, 0.f);
    }
    __syncthreads();
    if (tid < nj) {
        float l0 = bc3[0], l1 = bc3[1];
        for (int k = 0; k < 64; k++) {
            float h = h2S[tid][k];
            l0 = fmaf(h, Wc3[2 * k + 0], l0);
            l1 = fmaf(h, Wc3[2 * k + 1], l1);
        }
        labTab[plS[tid]] = (l1 > l0) ? 1 : 0;
    }
}

// ---------------- fast resolve (1 block, 1024 threads, LDS walk + scan) ----------------

__global__ void k_resolve2(const int* __restrict__ validIdx, const int* __restrict__ NvP,
                           const int* __restrict__ mask, const int* __restrict__ labTab,
                           int* fireFlag, int* kPref) {
    __shared__ int vIdxS[NVMAX];
    __shared__ int maskS[NVMAX];
    __shared__ int labS[NVMAX * NVMAX];
    __shared__ int fireS[NN];
    __shared__ int scanS[NN];
    int t = threadIdx.x;
    int Nv = *NvP;
    if (t < NVMAX) {
        int vi = (t < Nv) ? validIdx[t] : 0;
        vIdxS[t] = vi;
        maskS[t] = (t < Nv) ? mask[vi] : 0;
    }
    fireS[t] = 0;
    for (int idx = t; idx < Nv * NVMAX; idx += NN) labS[idx] = labTab[idx];
    __syncthreads();
    if (t == 0) {
        int k = 0;
        for (int v = 0; v < Nv; v++) {
            int fire = (maskS[v] > 0) ? 1 : labS[v * NVMAX + k];
            fireS[vIdxS[v]] = fire;
            k += fire;
        }
    }
    __syncthreads();
    int f0 = fireS[t];
    scanS[t] = f0;
    __syncthreads();
    for (int st = 1; st < NN; st <<= 1) {
        int u = (t >= st) ? scanS[t - st] : 0;
        __syncthreads();
        scanS[t] += u;
        __syncthreads();
    }
    kPref[t] = scanS[t] - f0;
    fireFlag[t] = f0;
}

// ---------------- fused final pass: JF nodes per block ----------------

__global__ void __launch_bounds__(256)
k_final2(const float* __restrict__ Emb, const int* __restrict__ kPref,
         const int* __restrict__ fireFlag, const int* __restrict__ mask,
         const float* __restrict__ pka, const int* __restrict__ vpos,
         const int* __restrict__ labTab,
         const float* __restrict__ Wg, const float* __restrict__ bg,
         const float* __restrict__ Wc1, const float* __restrict__ bc1,
         const float* __restrict__ Wc2, const float* __restrict__ bc2,
         const float* __restrict__ Wc3, const float* __restrict__ bc3,
         const float* __restrict__ Wr1, const float* __restrict__ br1,
         const float* __restrict__ Wr2, const float* __restrict__ br2,
         const float* __restrict__ Wr3, const float* __restrict__ br3,
         float* __restrict__ outLabels, float* __restrict__ outPreds,
         float* __restrict__ ceArr, float* __restrict__ regArr,
         float* __restrict__ corArr) {
    __shared__ float WgS[HID * HID];       // 64 KB
    __shared__ float rS[JF][HID];
    __shared__ float h1S[JF][256];
    __shared__ float h2S[JF][64];
    __shared__ float lgS[JF][2];
    __shared__ float prS[JF];
    __shared__ int kcS[JF];
    int tid = threadIdx.x;  // 256
    int i0 = blockIdx.x * JF;

    const float4* Wg4 = (const float4*)Wg;
    float4* Ws4 = (float4*)WgS;
    for (int idx = tid; idx < HID * HID / 4; idx += 256) Ws4[idx] = Wg4[idx];
    if (tid < HID) {
#pragma unroll
        for (int j = 0; j < JF; j++) rS[j][tid] = Emb[(i0 + j) * HID + tid];
    }
    if (tid < JF) kcS[tid] = kPref[i0 + tid];
    __syncthreads();
    int kc[JF]; int maxkc = 0;
#pragma unroll
    for (int j = 0; j < JF; j++) { kc[j] = kcS[j]; if (kc[j] > maxkc) maxkc = kc[j]; }

    int col = tid & (HID - 1);
    int slot = tid >> 7;
    int j0 = slot * 2, j1 = slot * 2 + 1;
    float bgc = bg[col];
    for (int t = 0; t < maxkc; t++) {
        float a00 = 0.f, a01 = 0.f, a02 = 0.f, a03 = 0.f;
        float a10 = 0.f, a11 = 0.f, a12 = 0.f, a13 = 0.f;
        for (int q = 0; q < HID; q += 4) {
            float w0 = WgS[(q + 0) * HID + col];
            float w1 = WgS[(q + 1) * HID + col];
            float w2 = WgS[(q + 2) * HID + col];
            float w3 = WgS[(q + 3) * HID + col];
            a00 = fmaf(rS[j0][q + 0], w0, a00);
            a01 = fmaf(rS[j0][q + 1], w1, a01);
            a02 = fmaf(rS[j0][q + 2], w2, a02);
            a03 = fmaf(rS[j0][q + 3], w3, a03);
            a10 = fmaf(rS[j1][q + 0], w0, a10);
            a11 = fmaf(rS[j1][q + 1], w1, a11);
            a12 = fmaf(rS[j1][q + 2], w2, a12);
            a13 = fmaf(rS[j1][q + 3], w3, a13);
        }
        float g0 = 1.0f - sigm(((a00 + a01) + (a02 + a03)) + bgc);
        float g1 = 1.0f - sigm(((a10 + a11) + (a12 + a13)) + bgc);
        __syncthreads();
        if (t < kc[j0]) rS[j0][col] *= g0;
        if (t < kc[j1]) rS[j1][col] *= g1;
        __syncthreads();
    }

    {
        float a[JF];
#pragma unroll
        for (int j = 0; j < JF; j++) a[j] = 0.f;
        for (int k = 0; k < HID; k++) {
            float w = Wc1[k * 256 + tid];
#pragma unroll
            for (int j = 0; j < JF; j++) a[j] = fmaf(rS[j][k], w, a[j]);
        }
        float b = bc1[tid];
#pragma unroll
        for (int j = 0; j < JF; j++) h1S[j][tid] = fmaxf(a[j] + b, 0.f);
    }
    __syncthreads();
    {
        int c2 = tid & 63, j = tid >> 6;
        float acc = 0.f;
        for (int k = 0; k < 256; k++) acc = fmaf(h1S[j][k], Wc2[k * 64 + c2], acc);
        h2S[j][c2] = fmaxf(acc + bc2[c2], 0.f);
    }
    __syncthreads();
    if (tid < 2 * JF) {
        int j = tid >> 1, c = tid & 1;
        float l = bc3[c];
        for (int k = 0; k < 64; k++) l = fmaf(h2S[j][k], Wc3[2 * k + c], l);
        lgS[j][c] = l;
    }
    __syncthreads();

    {
        float a[JF];
#pragma unroll
        for (int j = 0; j < JF; j++) a[j] = 0.f;
        for (int k = 0; k < HID; k++) {
            float w = Wr1[k * 256 + tid];
#pragma unroll
            for (int j = 0; j < JF; j++) a[j] = fmaf(rS[j][k], w, a[j]);
        }
        float b = br1[tid];
#pragma unroll
        for (int j = 0; j < JF; j++) h1S[j][tid] = fmaxf(a[j] + b, 0.f);
    }
    __syncthreads();
    {
        int c2 = tid & 63, j = tid >> 6;
        float acc = 0.f;
        for (int k = 0; k < 256; k++) acc = fmaf(h1S[j][k], Wr2[k * 64 + c2], acc);
        h2S[j][c2] = fmaxf(acc + br2[c2], 0.f);
    }
    __syncthreads();
    if (tid < JF) {
        float pr = br3[0];
        for (int k = 0; k < 64; k++) pr = fmaf(h2S[tid][k], Wr3[k], pr);
        prS[tid] = pr;
    }
    __syncthreads();

    if (tid < JF) {
        int j = tid, i = i0 + j;
        float l0 = lgS[j][0], l1 = lgS[j][1];
        int compLab = (l1 > l0) ? 1 : 0;
        int vp = vpos[i];
        int label = (vp >= 0 && mask[i] == 0) ? labTab[vp * NVMAX + kc[j]] : compLab;
        int target = (mask[i] > 0) ? 1 : 0;
        float mx = fmaxf(l0, l1);
        float lse = mx + logf(expf(l0 - mx) + expf(l1 - mx));
        float ce = lse - ((target == 1) ? l1 : l0);
        int reg_cond = (label == 1) || (mask[i] > 0);
        float p = sigm(prS[j]);
        p = fminf(fmaxf(p, 0.f), 14.f);
        outLabels[i] = (float)label;
        outPreds[i] = reg_cond ? p : 0.f;
        ceArr[i] = ce;
        corArr[i] = (label == target) ? 1.f : 0.f;
        if (fireFlag[i]) {
            float d = p - pka[i];
            regArr[i] = d * d;
        } else {
            regArr[i] = 0.f;
        }
    }
}

__global__ void k_loss(const float* __restrict__ ceArr, const float* __restrict__ regArr,
                       const float* __restrict__ corArr, float* __restrict__ out) {
    __shared__ float s[NN];
    int t = threadIdx.x;
    s[t] = ceArr[t]; __syncthreads();
    for (int st = 512; st > 0; st >>= 1) { if (t < st) s[t] += s[t + st]; __syncthreads(); }
    float cls = s[0]; __syncthreads();
    s[t] = regArr[t]; __syncthreads();
    for (int st = 512; st > 0; st >>= 1) { if (t < st) s[t] += s[t + st]; __syncthreads(); }
    float reg = s[0]; __syncthreads();
    s[t] = corArr[t]; __syncthreads();
    for (int st = 512; st > 0; st >>= 1) { if (t < st) s[t] += s[t + st]; __syncthreads(); }
    float cor = s[0];
    if (t == 0) {
        out[0] = cls + reg;
        out[1] = cls;
        out[2] = reg;
        out[3] = cor / (float)NN;
    }
}

// ---------------- launch ----------------

extern "C" void kernel_launch(void* const* d_in, const int* in_sizes, int n_in,
                              void* d_out, int out_size, void* d_ws, size_t ws_size,
                              hipStream_t stream) {
    const float* x    = (const float*)d_in[0];
    const float* ea   = (const float*)d_in[1];
    const float* pka  = (const float*)d_in[2];
    const int*   mask = (const int*)d_in[3];
    const int*   eidx = (const int*)d_in[4];
    const int*   rev  = (const int*)d_in[5];
    const float* Wi  = (const float*)d_in[6];  const float* bi  = (const float*)d_in[7];
    const float* Wh  = (const float*)d_in[8];  const float* bh  = (const float*)d_in[9];
    const float* Wo  = (const float*)d_in[10]; const float* bo  = (const float*)d_in[11];
    const float* Wnt = (const float*)d_in[12]; const float* bnt = (const float*)d_in[13];
    const float* Wc1 = (const float*)d_in[14]; const float* bc1 = (const float*)d_in[15];
    const float* Wc2 = (const float*)d_in[16]; const float* bc2 = (const float*)d_in[17];
    const float* Wc3 = (const float*)d_in[18]; const float* bc3 = (const float*)d_in[19];
    const float* Wr1 = (const float*)d_in[20]; const float* br1 = (const float*)d_in[21];
    const float* Wr2 = (const float*)d_in[22]; const float* br2 = (const float*)d_in[23];
    const float* Wr3 = (const float*)d_in[24]; const float* br3 = (const float*)d_in[25];
    const float* Wg  = (const float*)d_in[26]; const float* bg  = (const float*)d_in[27];

    const int* src = eidx;
    const int* dst = eidx + NE;

    char* w = (char*)d_ws;
    auto alloc = [&](size_t bytes) -> void* {
        void* p = (void*)w;
        w += ((bytes + 255) / 256) * 256;
        return p;
    };
    float* H0   = (float*)alloc((size_t)NE * HID * 4);
    float* HtA  = (float*)alloc((size_t)NE * HID * 4);
    float* HtB  = (float*)alloc((size_t)NE * HID * 4);
    float* agg  = (float*)alloc((size_t)NN * HID * 4);
    float* Emb  = (float*)alloc((size_t)NN * HID * 4);
    int* deg     = (int*)alloc(NN * 4);
    int* offs    = (int*)alloc((NN + 1) * 4);
    int* fillpos = (int*)alloc(NN * 4);
    int* elist   = (int*)alloc(NE * 4);
    int* validIdx= (int*)alloc(NVMAX * 4);
    int* NvP     = (int*)alloc(16);
    int* vpos    = (int*)alloc(NN * 4);
    int* fireFlag= (int*)alloc(NN * 4);
    int* kPref   = (int*)alloc(NN * 4);
    float* specSt= (float*)alloc((size_t)NVMAX * NVMAX * HID * 4);
    int* labTab  = (int*)alloc(NVMAX * NVMAX * 4);
    int* pairCnt = (int*)alloc(16);
    int* pairList= (int*)alloc(MAXPAIRS * 4);
    float* ceArr = (float*)alloc(NN * 4);
    float* regArr= (float*)alloc(NN * 4);
    float* corArr= (float*)alloc(NN * 4);

    float* outF = (float*)d_out;  // [labels 1024][preds 1024][loss 4]

    hipMemsetAsync(deg, 0, NN * 4, stream);

    k_count<<<NE / 256, 256, 0, stream>>>(dst, deg);
    k_prep<<<1, NN, 0, stream>>>(deg, offs, fillpos, pka, validIdx, NvP, vpos,
                                 mask, pairCnt, pairList);
    k_fill<<<NE / 256, 256, 0, stream>>>(dst, fillpos, elist);
    k_sort2<<<NN / 256, 256, 0, stream>>>(elist, offs);

    k_edge_init<<<NE / EB, HID, 0, stream>>>(x, ea, src, Wi, bi, H0, HtA);
    k_segsum<<<NN, HID, 0, stream>>>(HtA, elist, offs, agg);
    k_edge_update<<<NE / EB, HID, 0, stream>>>(H0, HtA, agg, src, rev, Wh, bh, HtB);
    k_segsum<<<NN, HID, 0, stream>>>(HtB, elist, offs, agg);
    k_edge_update<<<NE / EB, HID, 0, stream>>>(H0, HtB, agg, src, rev, Wh, bh, HtA);
    k_segsum<<<NN, HID, 0, stream>>>(HtA, elist, offs, agg);
    k_node_embed<<<NN, HID, 0, stream>>>(x, agg, Wnt, bnt, Wo, bo, Emb);

    k_chains3<<<NVMAX, 512, 0, stream>>>(Emb, validIdx, NvP, Wg, bg, specSt);
    k_table2<<<(MAXPAIRS + JT - 1) / JT, 256, 0, stream>>>(specSt, pairList, pairCnt,
                                                           Wc1, bc1, Wc2, bc2, Wc3, bc3, labTab);
    k_resolve2<<<1, NN, 0, stream>>>(validIdx, NvP, mask, labTab, fireFlag, kPref);

    k_final2<<<NN / JF, 256, 0, stream>>>(Emb, kPref, fireFlag, mask, pka, vpos, labTab,
                                          Wg, bg, Wc1, bc1, Wc2, bc2, Wc3, bc3,
                                          Wr1, br1, Wr2, br2, Wr3, br3,
                                          outF, outF + NN, ceArr, regArr, corArr);
    k_loss<<<1, NN, 0, stream>>>(ceArr, regArr, corArr, outF + 2 * NN);
}